// Round 6
// baseline (852.764 us; speedup 1.0000x reference)
//
#include <hip/hip_runtime.h>

#define NN 50000
#define NE 600000
#define HD 128
#define NL 4
#define NB 256
#define NO 10
#define BN_EPS 1e-5f
#define AGG_NPW 8
#define AGG_BLOCKS ((NN + 4 * AGG_NPW - 1) / (4 * AGG_NPW))

typedef short bf16x8 __attribute__((ext_vector_type(8)));
typedef float f32x4 __attribute__((ext_vector_type(4)));

__device__ __forceinline__ unsigned short f2bf(float f) {
    union { float f; unsigned int u; } x; x.f = f;
    unsigned int u = x.u;
    unsigned int r = (u + 0x7FFFu + ((u >> 16) & 1u)) >> 16;  // RNE
    return (unsigned short)r;
}
__device__ __forceinline__ float bf2f(unsigned short s) {
    union { unsigned int u; float f; } x; x.u = ((unsigned int)s) << 16;
    return x.f;
}

// ---------------- CSR build ----------------

__global__ void hist_kernel(const int* __restrict__ col, int* __restrict__ cnt, int e) {
    int i = blockIdx.x * blockDim.x + threadIdx.x;
    if (i < e) atomicAdd(&cnt[col[i]], 1);
}

// scan over M=N+1 elements + fused dinv
__global__ void scan1_kernel(const int* __restrict__ cnt, int* __restrict__ outp,
                             int* __restrict__ bsums, float* __restrict__ dinv,
                             int M, int n) {
    __shared__ int s[256];
    int tid = threadIdx.x;
    int base = blockIdx.x * 1024 + tid * 4;
    int v[4];
#pragma unroll
    for (int j = 0; j < 4; ++j) {
        int idx = base + j;
        v[j] = (idx < n) ? cnt[idx] : 0;
        if (idx < n) dinv[idx] = rsqrtf((float)(v[j] + 1));  // +1 self-loop
    }
    int tot = v[0] + v[1] + v[2] + v[3];
    s[tid] = tot;
    __syncthreads();
    for (int off = 1; off < 256; off <<= 1) {
        int x = (tid >= off) ? s[tid - off] : 0;
        __syncthreads();
        s[tid] += x;
        __syncthreads();
    }
    int run = (tid == 0) ? 0 : s[tid - 1];
#pragma unroll
    for (int j = 0; j < 4; ++j) {
        int idx = base + j;
        if (idx < M) outp[idx] = run;
        run += v[j];
    }
    if (tid == 255) bsums[blockIdx.x] = s[255];
}

__global__ void scan2_kernel(int* bsums, int nb) {
    if (threadIdx.x == 0 && blockIdx.x == 0) {
        int acc = 0;
        for (int i = 0; i < nb; ++i) { int v = bsums[i]; bsums[i] = acc; acc += v; }
    }
}

__global__ void scan3_kernel(int* __restrict__ outp, const int* __restrict__ bsums, int M) {
    int i = blockIdx.x * blockDim.x + threadIdx.x;
    if (i < M) outp[i] += bsums[i >> 10];
}

__global__ void place_kernel(const int* __restrict__ row, const int* __restrict__ col,
                             const float* __restrict__ dinv, const int* __restrict__ rp,
                             int* __restrict__ fill, int2* __restrict__ csr, int e) {
    int i = blockIdx.x * blockDim.x + threadIdx.x;
    if (i < e) {
        int r = row[i], c = col[i];
        int pos = atomicAdd(&fill[c], 1);
        int idx = rp[c] + pos;
        csr[idx] = make_int2(r, __float_as_int(dinv[r] * dinv[c]));
    }
}

// ---------------- weight transpose+convert: Wt[m][n][k] = bf16(Wsrc_m[k][n]) ----------------
__global__ void wconv_kernel(const float* __restrict__ W_enc, const float* __restrict__ W,
                             unsigned short* __restrict__ Wt) {
    int i = blockIdx.x * blockDim.x + threadIdx.x;
    if (i >= 5 * 16384) return;
    int m = i >> 14;
    int r = (i >> 7) & 127;  // dest row = n
    int k = i & 127;         // dest col = k
    const float* src = (m == 0) ? W_enc : (W + (size_t)(m - 1) * 16384);
    Wt[i] = f2bf(src[k * 128 + r]);
}

// ---------------- MFMA GEMM: C[n x 128] = A[n x 128] @ W[128 x 128] (+bias), C bf16 ----------------
// AMODE: 0 = fp32 A, 1 = bf16 A, 2 = fp32 A with fused BN(scale,shift)+ReLU
template <int AMODE>
__global__ __launch_bounds__(256) void gemm128_mfma(const void* __restrict__ Ap,
                                                    const unsigned short* __restrict__ Wt,
                                                    const float* __restrict__ bias,
                                                    const float* __restrict__ bnp,
                                                    unsigned short* __restrict__ Cp,
                                                    int nrows) {
    int wave = threadIdx.x >> 6;
    int lane = threadIdx.x & 63;
    int r16 = lane & 15;
    int kg = lane >> 4;
    int rowBase = blockIdx.x * 64 + wave * 16;
    int row = rowBase + r16;
    bool valid = row < nrows;

    bf16x8 afr[4];
#pragma unroll
    for (int s = 0; s < 4; ++s) {
        bf16x8 tt = {};
        int c0 = s * 32 + kg * 8;
        if constexpr (AMODE == 1) {
            const unsigned short* A = (const unsigned short*)Ap;
            if (valid) tt = *(const bf16x8*)&A[(size_t)row * 128 + c0];
        } else if constexpr (AMODE == 0) {
            const float* A = (const float*)Ap;
            if (valid) {
                const float* p = &A[(size_t)row * 128 + c0];
                float4 u0 = *(const float4*)p;
                float4 u1 = *(const float4*)(p + 4);
                tt[0] = (short)f2bf(u0.x); tt[1] = (short)f2bf(u0.y);
                tt[2] = (short)f2bf(u0.z); tt[3] = (short)f2bf(u0.w);
                tt[4] = (short)f2bf(u1.x); tt[5] = (short)f2bf(u1.y);
                tt[6] = (short)f2bf(u1.z); tt[7] = (short)f2bf(u1.w);
            }
        } else {
            const float* A = (const float*)Ap;
            if (valid) {
                const float* p = &A[(size_t)row * 128 + c0];
                float4 u0 = *(const float4*)p;
                float4 u1 = *(const float4*)(p + 4);
                float4 s0 = *(const float4*)&bnp[c0];
                float4 s1 = *(const float4*)&bnp[c0 + 4];
                float4 h0 = *(const float4*)&bnp[128 + c0];
                float4 h1 = *(const float4*)&bnp[128 + c0 + 4];
                tt[0] = (short)f2bf(fmaxf(u0.x * s0.x + h0.x, 0.f));
                tt[1] = (short)f2bf(fmaxf(u0.y * s0.y + h0.y, 0.f));
                tt[2] = (short)f2bf(fmaxf(u0.z * s0.z + h0.z, 0.f));
                tt[3] = (short)f2bf(fmaxf(u0.w * s0.w + h0.w, 0.f));
                tt[4] = (short)f2bf(fmaxf(u1.x * s1.x + h1.x, 0.f));
                tt[5] = (short)f2bf(fmaxf(u1.y * s1.y + h1.y, 0.f));
                tt[6] = (short)f2bf(fmaxf(u1.z * s1.z + h1.z, 0.f));
                tt[7] = (short)f2bf(fmaxf(u1.w * s1.w + h1.w, 0.f));
            }
        }
        afr[s] = tt;
    }

    f32x4 acc[8];
#pragma unroll
    for (int n = 0; n < 8; ++n) acc[n] = (f32x4){0.f, 0.f, 0.f, 0.f};

#pragma unroll
    for (int n = 0; n < 8; ++n) {
        const unsigned short* wp = &Wt[(size_t)(n * 16 + r16) * 128 + kg * 8];
#pragma unroll
        for (int s = 0; s < 4; ++s) {
            bf16x8 bfr = *(const bf16x8*)&wp[s * 32];
            acc[n] = __builtin_amdgcn_mfma_f32_16x16x32_bf16(afr[s], bfr, acc[n], 0, 0, 0);
        }
    }

    // C/D: lane holds rows kg*4+i, col r16 (within tile)
#pragma unroll
    for (int n = 0; n < 8; ++n) {
        int col = n * 16 + r16;
        float bv = bias ? bias[col] : 0.f;
#pragma unroll
        for (int i = 0; i < 4; ++i) {
            int orow = rowBase + kg * 4 + i;
            if (orow < nrows)
                Cp[(size_t)orow * 128 + col] = f2bf(acc[n][i] + bv);
        }
    }
}

// ---------------- Aggregation + fused BN stats ----------------
// agg[i] = b + dinv_i^2 * t[i] + sum_e w_e * t[src_e]; each wave handles AGG_NPW nodes,
// accumulates (sum, sumsq) in registers, block-reduces, atomicAdds into 8 replica buffers.
// Last block reduces replicas -> bnp, self-resets (deterministic end-state for replay).
__global__ __launch_bounds__(256) void aggregate_kernel(const unsigned short* __restrict__ t,
                                                        const int* __restrict__ rp,
                                                        const int2* __restrict__ csr,
                                                        const float* __restrict__ dinv,
                                                        const float* __restrict__ bvec,
                                                        float* __restrict__ agg,
                                                        float* __restrict__ bnsums8,
                                                        int* __restrict__ counter,
                                                        const float* __restrict__ gamma,
                                                        const float* __restrict__ beta,
                                                        float* __restrict__ bnp, int n) {
    int wave = threadIdx.x >> 6;
    int lane = threadIdx.x & 63;
    int c = lane * 2;
    float bx = bvec[c], by = bvec[c + 1];
    int nodeBase = (blockIdx.x * 4 + wave) * AGG_NPW;
    float sx = 0.f, sy = 0.f, qx = 0.f, qy = 0.f;
    for (int j = 0; j < AGG_NPW; ++j) {
        int wid = nodeBase + j;
        if (wid >= n) break;
        float di = dinv[wid];
        float sw = di * di;
        unsigned int u = *(const unsigned int*)&t[(size_t)wid * 128 + c];
        float ax = sw * bf2f((unsigned short)(u & 0xffff)) + bx;
        float ay = sw * bf2f((unsigned short)(u >> 16)) + by;
        int e = rp[wid], e1 = rp[wid + 1];
        for (; e + 3 < e1; e += 4) {
            int2 ew0 = csr[e], ew1 = csr[e + 1], ew2 = csr[e + 2], ew3 = csr[e + 3];
            unsigned int u0 = *(const unsigned int*)&t[(size_t)ew0.x * 128 + c];
            unsigned int u1 = *(const unsigned int*)&t[(size_t)ew1.x * 128 + c];
            unsigned int u2 = *(const unsigned int*)&t[(size_t)ew2.x * 128 + c];
            unsigned int u3 = *(const unsigned int*)&t[(size_t)ew3.x * 128 + c];
            float w0 = __int_as_float(ew0.y), w1 = __int_as_float(ew1.y);
            float w2 = __int_as_float(ew2.y), w3 = __int_as_float(ew3.y);
            ax += w0 * bf2f((unsigned short)(u0 & 0xffff)) + w1 * bf2f((unsigned short)(u1 & 0xffff));
            ay += w0 * bf2f((unsigned short)(u0 >> 16)) + w1 * bf2f((unsigned short)(u1 >> 16));
            ax += w2 * bf2f((unsigned short)(u2 & 0xffff)) + w3 * bf2f((unsigned short)(u3 & 0xffff));
            ay += w2 * bf2f((unsigned short)(u2 >> 16)) + w3 * bf2f((unsigned short)(u3 >> 16));
        }
        for (; e < e1; ++e) {
            int2 ew = csr[e];
            unsigned int u0 = *(const unsigned int*)&t[(size_t)ew.x * 128 + c];
            float w0 = __int_as_float(ew.y);
            ax += w0 * bf2f((unsigned short)(u0 & 0xffff));
            ay += w0 * bf2f((unsigned short)(u0 >> 16));
        }
        *(float2*)&agg[(size_t)wid * 128 + c] = make_float2(ax, ay);
        sx += ax; qx += ax * ax;
        sy += ay; qy += ay * ay;
    }

    __shared__ float4 st[4][64];
    __shared__ int lastflag;
    st[wave][lane] = make_float4(sx, sy, qx, qy);
    __syncthreads();
    if (wave == 0) {
        float4 a = st[0][lane], b2 = st[1][lane], c2 = st[2][lane], d2 = st[3][lane];
        float ssx = a.x + b2.x + c2.x + d2.x;
        float ssy = a.y + b2.y + c2.y + d2.y;
        float qqx = a.z + b2.z + c2.z + d2.z;
        float qqy = a.w + b2.w + c2.w + d2.w;
        float* rep = bnsums8 + (size_t)(blockIdx.x & 7) * 256;
        atomicAdd(&rep[c], ssx);
        atomicAdd(&rep[c + 1], ssy);
        atomicAdd(&rep[128 + c], qqx);
        atomicAdd(&rep[128 + c + 1], qqy);
    }
    __threadfence();
    __syncthreads();
    if (threadIdx.x == 0) lastflag = (atomicAdd(counter, 1) == AGG_BLOCKS - 1);
    __syncthreads();
    if (!lastflag) return;

    // finalize: reduce 8 replicas, compute bnp, zero replicas + counter
    int i = threadIdx.x;  // 0..255
    float acc2 = 0.f;
#pragma unroll
    for (int rsel = 0; rsel < 8; ++rsel) {
        acc2 += bnsums8[(size_t)rsel * 256 + i];
        bnsums8[(size_t)rsel * 256 + i] = 0.f;
    }
    __shared__ float red[256];
    red[i] = acc2;
    __syncthreads();
    if (i < 128) {
        float fn = (float)n;
        float mean = red[i] / fn;
        float var = fmaxf(red[128 + i] / fn - mean * mean, 0.f);
        float sc = gamma[i] * rsqrtf(var + BN_EPS);
        bnp[i] = sc;
        bnp[128 + i] = beta[i] - mean * sc;
        if (i == 0) *counter = 0;
    }
}

// ---------------- Pool (BN+ReLU fused) + classifier, one block per graph ----------------
__global__ __launch_bounds__(256) void pool_cls_kernel(const float* __restrict__ agg,
                                                       const float* __restrict__ bnp,
                                                       const int* __restrict__ batch,
                                                       const float* __restrict__ Wc,
                                                       const float* __restrict__ bc,
                                                       float* __restrict__ out, int n) {
    int b = blockIdx.x;  // graph id, 0..NB-1
    int tid = threadIdx.x;
    // row range of graph b in sorted batch
    int lo = 0, hi = n;
    while (lo < hi) { int mid = (lo + hi) >> 1; if (batch[mid] < b) lo = mid + 1; else hi = mid; }
    int start = lo;
    hi = n;
    while (lo < hi) { int mid = (lo + hi) >> 1; if (batch[mid] <= b) lo = mid + 1; else hi = mid; }
    int end = lo;

    int c4 = tid & 31, rs = tid >> 5;
    f32x4 sc = *(const f32x4*)&bnp[c4 * 4];
    f32x4 sh = *(const f32x4*)&bnp[128 + c4 * 4];
    f32x4 acc = {0.f, 0.f, 0.f, 0.f};
    for (int r = start + rs; r < end; r += 8) {
        f32x4 v = *(const f32x4*)&agg[(size_t)r * 128 + c4 * 4];
        f32x4 y = v * sc + sh;
#pragma unroll
        for (int k = 0; k < 4; ++k) y[k] = fmaxf(y[k], 0.f);
        acc += y;
    }
    __shared__ f32x4 ls[256];
    __shared__ float g[128];
    ls[tid] = acc;
    __syncthreads();
    if (tid < 32) {
        f32x4 ss = ls[tid];
#pragma unroll
        for (int j = 1; j < 8; ++j) ss += ls[tid + 32 * j];
        float invc = 1.0f / fmaxf((float)(end - start), 1.0f);
#pragma unroll
        for (int k = 0; k < 4; ++k) g[tid * 4 + k] = ss[k] * invc;
    }
    __syncthreads();
    if (tid < NO) {
        float s = bc[tid];
        for (int c = 0; c < 128; ++c) s += g[c] * Wc[c * NO + tid];
        out[b * NO + tid] = s;
    }
}

// ---------------- host launch ----------------
extern "C" void kernel_launch(void* const* d_in, const int* in_sizes, int n_in,
                              void* d_out, int out_size, void* d_ws, size_t ws_size,
                              hipStream_t stream) {
    const float* x      = (const float*)d_in[0];
    const int*   eidx   = (const int*)d_in[1];
    const int*   batch  = (const int*)d_in[2];
    const float* W_enc  = (const float*)d_in[3];
    const float* b_enc  = (const float*)d_in[4];
    const float* W      = (const float*)d_in[5];
    const float* b      = (const float*)d_in[6];
    const float* gamma  = (const float*)d_in[7];
    const float* beta   = (const float*)d_in[8];
    const float* W_cls  = (const float*)d_in[9];
    const float* b_cls  = (const float*)d_in[10];
    float* out = (float*)d_out;

    const int* erow = eidx;
    const int* ecol = eidx + NE;

    // workspace layout
    float* agg      = (float*)d_ws;                      // NN*HD fp32
    float* dinv     = agg + (size_t)NN * HD;             // NN
    float* bnsums8  = dinv + NN;                         // 8*256
    int*   bncnt    = (int*)(bnsums8 + 8 * 256);         // 4 ints (1 used)
    float* bnp      = (float*)(bncnt + 4);               // 256
    int2*  csr      = (int2*)(bnp + 256);                // NE int2
    unsigned short* h  = (unsigned short*)(csr + NE);    // NN*HD bf16
    unsigned short* t  = h + (size_t)NN * HD;            // NN*HD bf16
    unsigned short* Wt = t + (size_t)NN * HD;            // 5*16384 bf16
    int* cnt      = (int*)(Wt + 5 * 16384);              // NN
    int* fill     = cnt + NN;                            // NN (adjacent -> one memset)
    int* rp       = fill + NN;                           // NN+1
    int* bsums    = rp + NN + 1;                         // 64

    hipMemsetAsync(cnt, 0, 2 * NN * sizeof(int), stream);
    hipMemsetAsync(bnsums8, 0, 8 * 256 * sizeof(float) + 4 * sizeof(int), stream);

    // CSR build (once; reused across layers)
    hist_kernel<<<(NE + 255) / 256, 256, 0, stream>>>(ecol, cnt, NE);
    int M = NN + 1;
    int nscan = (M + 1023) / 1024;
    scan1_kernel<<<nscan, 256, 0, stream>>>(cnt, rp, bsums, dinv, M, NN);
    scan2_kernel<<<1, 64, 0, stream>>>(bsums, nscan);
    scan3_kernel<<<(M + 255) / 256, 256, 0, stream>>>(rp, bsums, M);
    place_kernel<<<(NE + 255) / 256, 256, 0, stream>>>(erow, ecol, dinv, rp, fill, csr, NE);

    // weights -> bf16 transposed
    wconv_kernel<<<(5 * 16384 + 255) / 256, 256, 0, stream>>>(W_enc, W, Wt);

    int gemmBlocks = (NN + 63) / 64;
    // encoder: x fp32 -> h bf16
    gemm128_mfma<0><<<gemmBlocks, 256, 0, stream>>>(x, Wt, b_enc, nullptr, h, NN);

    for (int l = 0; l < NL; ++l) {
        if (l == 0)
            gemm128_mfma<1><<<gemmBlocks, 256, 0, stream>>>(
                h, Wt + (size_t)(l + 1) * 16384, nullptr, nullptr, t, NN);
        else
            gemm128_mfma<2><<<gemmBlocks, 256, 0, stream>>>(
                agg, Wt + (size_t)(l + 1) * 16384, nullptr, bnp, t, NN);
        aggregate_kernel<<<AGG_BLOCKS, 256, 0, stream>>>(t, rp, csr, dinv,
                                                         b + (size_t)l * HD, agg,
                                                         bnsums8, bncnt,
                                                         gamma + (size_t)l * HD,
                                                         beta + (size_t)l * HD, bnp, NN);
    }

    pool_cls_kernel<<<NB, 256, 0, stream>>>(agg, bnp, batch, W_cls, b_cls, out, NN);
}

// Round 7
// 678.865 us; speedup vs baseline: 1.2562x; 1.2562x over previous
//
#include <hip/hip_runtime.h>

#define NN 50000
#define NE 600000
#define HD 128
#define NL 4
#define NB 256
#define NO 10
#define BN_EPS 1e-5f

typedef short bf16x8 __attribute__((ext_vector_type(8)));
typedef float f32x4 __attribute__((ext_vector_type(4)));

__device__ __forceinline__ unsigned short f2bf(float f) {
    union { float f; unsigned int u; } x; x.f = f;
    unsigned int u = x.u;
    unsigned int r = (u + 0x7FFFu + ((u >> 16) & 1u)) >> 16;  // RNE
    return (unsigned short)r;
}
__device__ __forceinline__ float bf2f(unsigned short s) {
    union { unsigned int u; float f; } x; x.u = ((unsigned int)s) << 16;
    return x.f;
}

// ---------------- CSR build ----------------

__global__ void hist_kernel(const int* __restrict__ col, int* __restrict__ cnt, int e) {
    int i = blockIdx.x * blockDim.x + threadIdx.x;
    if (i < e) atomicAdd(&cnt[col[i]], 1);
}

// scan over M=N+1 elements + fused dinv
__global__ void scan1_kernel(const int* __restrict__ cnt, int* __restrict__ outp,
                             int* __restrict__ bsums, float* __restrict__ dinv,
                             int M, int n) {
    __shared__ int s[256];
    int tid = threadIdx.x;
    int base = blockIdx.x * 1024 + tid * 4;
    int v[4];
#pragma unroll
    for (int j = 0; j < 4; ++j) {
        int idx = base + j;
        v[j] = (idx < n) ? cnt[idx] : 0;
        if (idx < n) dinv[idx] = rsqrtf((float)(v[j] + 1));  // +1 self-loop
    }
    int tot = v[0] + v[1] + v[2] + v[3];
    s[tid] = tot;
    __syncthreads();
    for (int off = 1; off < 256; off <<= 1) {
        int x = (tid >= off) ? s[tid - off] : 0;
        __syncthreads();
        s[tid] += x;
        __syncthreads();
    }
    int run = (tid == 0) ? 0 : s[tid - 1];
#pragma unroll
    for (int j = 0; j < 4; ++j) {
        int idx = base + j;
        if (idx < M) outp[idx] = run;
        run += v[j];
    }
    if (tid == 255) bsums[blockIdx.x] = s[255];
}

__global__ void scan2_kernel(int* bsums, int nb) {
    if (threadIdx.x == 0 && blockIdx.x == 0) {
        int acc = 0;
        for (int i = 0; i < nb; ++i) { int v = bsums[i]; bsums[i] = acc; acc += v; }
    }
}

__global__ void scan3_kernel(int* __restrict__ outp, const int* __restrict__ bsums, int M) {
    int i = blockIdx.x * blockDim.x + threadIdx.x;
    if (i < M) outp[i] += bsums[i >> 10];
}

__global__ void place_kernel(const int* __restrict__ row, const int* __restrict__ col,
                             const float* __restrict__ dinv, const int* __restrict__ rp,
                             int* __restrict__ fill, int2* __restrict__ csr, int e) {
    int i = blockIdx.x * blockDim.x + threadIdx.x;
    if (i < e) {
        int r = row[i], c = col[i];
        int pos = atomicAdd(&fill[c], 1);
        int idx = rp[c] + pos;
        csr[idx] = make_int2(r, __float_as_int(dinv[r] * dinv[c]));
    }
}

// ---------------- weight transpose+convert: Wt[m][n][k] = bf16(Wsrc_m[k][n]) ----------------
__global__ void wconv_kernel(const float* __restrict__ W_enc, const float* __restrict__ W,
                             unsigned short* __restrict__ Wt) {
    int i = blockIdx.x * blockDim.x + threadIdx.x;
    if (i >= 5 * 16384) return;
    int m = i >> 14;
    int r = (i >> 7) & 127;  // dest row = n
    int k = i & 127;         // dest col = k
    const float* src = (m == 0) ? W_enc : (W + (size_t)(m - 1) * 16384);
    Wt[i] = f2bf(src[k * 128 + r]);
}

// ---------------- MFMA GEMM: C[n x 128] = A[n x 128] @ W[128 x 128] (+bias), C bf16 ----------------
// AMODE: 0 = fp32 A, 1 = bf16 A, 2 = fp32 A with fused BN(scale,shift)+ReLU
template <int AMODE>
__global__ __launch_bounds__(256) void gemm128_mfma(const void* __restrict__ Ap,
                                                    const unsigned short* __restrict__ Wt,
                                                    const float* __restrict__ bias,
                                                    const float* __restrict__ bnp,
                                                    unsigned short* __restrict__ Cp,
                                                    int nrows) {
    int wave = threadIdx.x >> 6;
    int lane = threadIdx.x & 63;
    int r16 = lane & 15;
    int kg = lane >> 4;
    int rowBase = blockIdx.x * 64 + wave * 16;
    int row = rowBase + r16;
    bool valid = row < nrows;

    bf16x8 afr[4];
#pragma unroll
    for (int s = 0; s < 4; ++s) {
        bf16x8 tt = {};
        int c0 = s * 32 + kg * 8;
        if constexpr (AMODE == 1) {
            const unsigned short* A = (const unsigned short*)Ap;
            if (valid) tt = *(const bf16x8*)&A[(size_t)row * 128 + c0];
        } else if constexpr (AMODE == 0) {
            const float* A = (const float*)Ap;
            if (valid) {
                const float* p = &A[(size_t)row * 128 + c0];
                float4 u0 = *(const float4*)p;
                float4 u1 = *(const float4*)(p + 4);
                tt[0] = (short)f2bf(u0.x); tt[1] = (short)f2bf(u0.y);
                tt[2] = (short)f2bf(u0.z); tt[3] = (short)f2bf(u0.w);
                tt[4] = (short)f2bf(u1.x); tt[5] = (short)f2bf(u1.y);
                tt[6] = (short)f2bf(u1.z); tt[7] = (short)f2bf(u1.w);
            }
        } else {
            const float* A = (const float*)Ap;
            if (valid) {
                const float* p = &A[(size_t)row * 128 + c0];
                float4 u0 = *(const float4*)p;
                float4 u1 = *(const float4*)(p + 4);
                float4 s0 = *(const float4*)&bnp[c0];
                float4 s1 = *(const float4*)&bnp[c0 + 4];
                float4 h0 = *(const float4*)&bnp[128 + c0];
                float4 h1 = *(const float4*)&bnp[128 + c0 + 4];
                tt[0] = (short)f2bf(fmaxf(u0.x * s0.x + h0.x, 0.f));
                tt[1] = (short)f2bf(fmaxf(u0.y * s0.y + h0.y, 0.f));
                tt[2] = (short)f2bf(fmaxf(u0.z * s0.z + h0.z, 0.f));
                tt[3] = (short)f2bf(fmaxf(u0.w * s0.w + h0.w, 0.f));
                tt[4] = (short)f2bf(fmaxf(u1.x * s1.x + h1.x, 0.f));
                tt[5] = (short)f2bf(fmaxf(u1.y * s1.y + h1.y, 0.f));
                tt[6] = (short)f2bf(fmaxf(u1.z * s1.z + h1.z, 0.f));
                tt[7] = (short)f2bf(fmaxf(u1.w * s1.w + h1.w, 0.f));
            }
        }
        afr[s] = tt;
    }

    f32x4 acc[8];
#pragma unroll
    for (int n = 0; n < 8; ++n) acc[n] = (f32x4){0.f, 0.f, 0.f, 0.f};

#pragma unroll
    for (int n = 0; n < 8; ++n) {
        const unsigned short* wp = &Wt[(size_t)(n * 16 + r16) * 128 + kg * 8];
#pragma unroll
        for (int s = 0; s < 4; ++s) {
            bf16x8 bfr = *(const bf16x8*)&wp[s * 32];
            acc[n] = __builtin_amdgcn_mfma_f32_16x16x32_bf16(afr[s], bfr, acc[n], 0, 0, 0);
        }
    }

    // C/D: lane holds rows kg*4+i, col r16 (within tile)
#pragma unroll
    for (int n = 0; n < 8; ++n) {
        int col = n * 16 + r16;
        float bv = bias ? bias[col] : 0.f;
#pragma unroll
        for (int i = 0; i < 4; ++i) {
            int orow = rowBase + kg * 4 + i;
            if (orow < nrows)
                Cp[(size_t)orow * 128 + col] = f2bf(acc[n][i] + bv);
        }
    }
}

// ---------------- Aggregation: agg[i] = b + dinv_i^2 * t[i] + sum_e w_e * t[src_e] ----------------
// One wave per node (max TLP for the latency-bound gather).
__global__ __launch_bounds__(256) void aggregate_kernel(const unsigned short* __restrict__ t,
                                                        const int* __restrict__ rp,
                                                        const int2* __restrict__ csr,
                                                        const float* __restrict__ dinv,
                                                        const float* __restrict__ bvec,
                                                        float* __restrict__ agg, int n) {
    int wid = blockIdx.x * 4 + (threadIdx.x >> 6);
    int lane = threadIdx.x & 63;
    if (wid >= n) return;
    int c = lane * 2;
    float di = dinv[wid];
    float sw = di * di;
    unsigned int u = *(const unsigned int*)&t[(size_t)wid * 128 + c];
    float2 acc;
    acc.x = sw * bf2f((unsigned short)(u & 0xffff)) + bvec[c];
    acc.y = sw * bf2f((unsigned short)(u >> 16)) + bvec[c + 1];
    int e = rp[wid], e1 = rp[wid + 1];
    for (; e + 3 < e1; e += 4) {
        int2 ew0 = csr[e], ew1 = csr[e + 1], ew2 = csr[e + 2], ew3 = csr[e + 3];
        unsigned int u0 = *(const unsigned int*)&t[(size_t)ew0.x * 128 + c];
        unsigned int u1 = *(const unsigned int*)&t[(size_t)ew1.x * 128 + c];
        unsigned int u2 = *(const unsigned int*)&t[(size_t)ew2.x * 128 + c];
        unsigned int u3 = *(const unsigned int*)&t[(size_t)ew3.x * 128 + c];
        float w0 = __int_as_float(ew0.y), w1 = __int_as_float(ew1.y);
        float w2 = __int_as_float(ew2.y), w3 = __int_as_float(ew3.y);
        acc.x += w0 * bf2f((unsigned short)(u0 & 0xffff)) + w1 * bf2f((unsigned short)(u1 & 0xffff));
        acc.y += w0 * bf2f((unsigned short)(u0 >> 16)) + w1 * bf2f((unsigned short)(u1 >> 16));
        acc.x += w2 * bf2f((unsigned short)(u2 & 0xffff)) + w3 * bf2f((unsigned short)(u3 & 0xffff));
        acc.y += w2 * bf2f((unsigned short)(u2 >> 16)) + w3 * bf2f((unsigned short)(u3 >> 16));
    }
    for (; e < e1; ++e) {
        int2 ew = csr[e];
        unsigned int u0 = *(const unsigned int*)&t[(size_t)ew.x * 128 + c];
        float w0 = __int_as_float(ew.y);
        acc.x += w0 * bf2f((unsigned short)(u0 & 0xffff));
        acc.y += w0 * bf2f((unsigned short)(u0 >> 16));
    }
    *(float2*)&agg[(size_t)wid * 128 + c] = acc;
}

// ---------------- BatchNorm stats: block partials + vectorized last-block finalize ----------------
// Stage 1: 512 blocks plain-store 256-float partials (128 sums + 128 sumsqs). No data atomics.
// Stage 2 (last block via counter): f32x4 coalesced reduce of 512KB partials, writes bnp, self-resets.
#define BN_BLOCKS 512
__global__ __launch_bounds__(512) void bn_stats_kernel(const float* __restrict__ agg,
                                                       float* __restrict__ partials,
                                                       int* __restrict__ counter,
                                                       const float* __restrict__ gamma,
                                                       const float* __restrict__ beta,
                                                       float* __restrict__ bnp, int n) {
    int tid = threadIdx.x;
    int c4 = tid & 31, rs = tid >> 5;  // 32 channel-quads x 16 row-streams
    f32x4 s = {0.f, 0.f, 0.f, 0.f}, q = {0.f, 0.f, 0.f, 0.f};
    for (int r = blockIdx.x * 16 + rs; r < n; r += BN_BLOCKS * 16) {
        f32x4 v = *(const f32x4*)&agg[(size_t)r * 128 + c4 * 4];
        s += v;
        q += v * v;
    }
    __shared__ f32x4 ls[512], lq[512];
    __shared__ int lastflag;
    ls[tid] = s;
    lq[tid] = q;
    __syncthreads();
    if (tid < 32) {
        f32x4 ss = ls[tid], qq = lq[tid];
#pragma unroll
        for (int j = 1; j < 16; ++j) { ss += ls[tid + 32 * j]; qq += lq[tid + 32 * j]; }
        float* pb = partials + (size_t)blockIdx.x * 256;
        *(f32x4*)&pb[tid * 4] = ss;          // channels 4*tid.. -> sums at [0,128)
        *(f32x4*)&pb[128 + tid * 4] = qq;    // sumsqs at [128,256)
    }
    __threadfence();
    __syncthreads();
    if (tid == 0) lastflag = (atomicAdd(counter, 1) == BN_BLOCKS - 1);
    __syncthreads();
    if (!lastflag) return;

    // vectorized coalesced reduce: thread t sums f32x4 column (t&63) over blocks (t>>6 interleave)
    f32x4 accv = {0.f, 0.f, 0.f, 0.f};
    int col4 = tid & 63, g = tid >> 6;
#pragma unroll 8
    for (int bb = g; bb < BN_BLOCKS; bb += 8)
        accv += *(const f32x4*)&partials[(size_t)bb * 256 + col4 * 4];
    __shared__ f32x4 redv[512];
    redv[tid] = accv;
    __syncthreads();
    __shared__ float red[256];
    if (tid < 64) {
        f32x4 tot = redv[tid];
#pragma unroll
        for (int j = 1; j < 8; ++j) tot += redv[tid + 64 * j];
        *(f32x4*)&red[tid * 4] = tot;
    }
    __syncthreads();
    if (tid < 128) {
        float fn = (float)n;
        float mean = red[tid] / fn;
        float var = fmaxf(red[128 + tid] / fn - mean * mean, 0.f);
        float sc = gamma[tid] * rsqrtf(var + BN_EPS);
        bnp[tid] = sc;
        bnp[128 + tid] = beta[tid] - mean * sc;
        if (tid == 0) *counter = 0;  // self-reset for next layer / replay
    }
}

// ---------------- Pool (BN+ReLU fused) + classifier, one block per graph ----------------
__global__ __launch_bounds__(256) void pool_cls_kernel(const float* __restrict__ agg,
                                                       const float* __restrict__ bnp,
                                                       const int* __restrict__ batch,
                                                       const float* __restrict__ Wc,
                                                       const float* __restrict__ bc,
                                                       float* __restrict__ out, int n) {
    int b = blockIdx.x;  // graph id, 0..NB-1
    int tid = threadIdx.x;
    // row range of graph b in sorted batch
    int lo = 0, hi = n;
    while (lo < hi) { int mid = (lo + hi) >> 1; if (batch[mid] < b) lo = mid + 1; else hi = mid; }
    int start = lo;
    hi = n;
    while (lo < hi) { int mid = (lo + hi) >> 1; if (batch[mid] <= b) lo = mid + 1; else hi = mid; }
    int end = lo;

    int c4 = tid & 31, rs = tid >> 5;
    f32x4 sc = *(const f32x4*)&bnp[c4 * 4];
    f32x4 sh = *(const f32x4*)&bnp[128 + c4 * 4];
    f32x4 acc = {0.f, 0.f, 0.f, 0.f};
    for (int r = start + rs; r < end; r += 8) {
        f32x4 v = *(const f32x4*)&agg[(size_t)r * 128 + c4 * 4];
        f32x4 y = v * sc + sh;
#pragma unroll
        for (int k = 0; k < 4; ++k) y[k] = fmaxf(y[k], 0.f);
        acc += y;
    }
    __shared__ f32x4 ls[256];
    __shared__ float g[128];
    ls[tid] = acc;
    __syncthreads();
    if (tid < 32) {
        f32x4 ss = ls[tid];
#pragma unroll
        for (int j = 1; j < 8; ++j) ss += ls[tid + 32 * j];
        float invc = 1.0f / fmaxf((float)(end - start), 1.0f);
#pragma unroll
        for (int k = 0; k < 4; ++k) g[tid * 4 + k] = ss[k] * invc;
    }
    __syncthreads();
    if (tid < NO) {
        float s = bc[tid];
        for (int c = 0; c < 128; ++c) s += g[c] * Wc[c * NO + tid];
        out[b * NO + tid] = s;
    }
}

// ---------------- host launch ----------------
extern "C" void kernel_launch(void* const* d_in, const int* in_sizes, int n_in,
                              void* d_out, int out_size, void* d_ws, size_t ws_size,
                              hipStream_t stream) {
    const float* x      = (const float*)d_in[0];
    const int*   eidx   = (const int*)d_in[1];
    const int*   batch  = (const int*)d_in[2];
    const float* W_enc  = (const float*)d_in[3];
    const float* b_enc  = (const float*)d_in[4];
    const float* W      = (const float*)d_in[5];
    const float* b      = (const float*)d_in[6];
    const float* gamma  = (const float*)d_in[7];
    const float* beta   = (const float*)d_in[8];
    const float* W_cls  = (const float*)d_in[9];
    const float* b_cls  = (const float*)d_in[10];
    float* out = (float*)d_out;

    const int* erow = eidx;
    const int* ecol = eidx + NE;

    // workspace layout
    float* agg      = (float*)d_ws;                      // NN*HD fp32
    float* dinv     = agg + (size_t)NN * HD;             // NN
    float* partials = dinv + NN;                         // BN_BLOCKS*256
    int*   bncnt    = (int*)(partials + BN_BLOCKS * 256);  // 4 ints (1 used)
    float* bnp      = (float*)(bncnt + 4);               // 256
    int2*  csr      = (int2*)(bnp + 256);                // NE int2
    unsigned short* h  = (unsigned short*)(csr + NE);    // NN*HD bf16
    unsigned short* t  = h + (size_t)NN * HD;            // NN*HD bf16
    unsigned short* Wt = t + (size_t)NN * HD;            // 5*16384 bf16
    int* cnt      = (int*)(Wt + 5 * 16384);              // NN
    int* fill     = cnt + NN;                            // NN (adjacent -> one memset)
    int* rp       = fill + NN;                           // NN+1
    int* bsums    = rp + NN + 1;                         // 64

    hipMemsetAsync(cnt, 0, 2 * NN * sizeof(int), stream);
    hipMemsetAsync(bncnt, 0, 4 * sizeof(int), stream);

    // CSR build (once; reused across layers)
    hist_kernel<<<(NE + 255) / 256, 256, 0, stream>>>(ecol, cnt, NE);
    int M = NN + 1;
    int nscan = (M + 1023) / 1024;
    scan1_kernel<<<nscan, 256, 0, stream>>>(cnt, rp, bsums, dinv, M, NN);
    scan2_kernel<<<1, 64, 0, stream>>>(bsums, nscan);
    scan3_kernel<<<(M + 255) / 256, 256, 0, stream>>>(rp, bsums, M);
    place_kernel<<<(NE + 255) / 256, 256, 0, stream>>>(erow, ecol, dinv, rp, fill, csr, NE);

    // weights -> bf16 transposed
    wconv_kernel<<<(5 * 16384 + 255) / 256, 256, 0, stream>>>(W_enc, W, Wt);

    int gemmBlocks = (NN + 63) / 64;
    // encoder: x fp32 -> h bf16
    gemm128_mfma<0><<<gemmBlocks, 256, 0, stream>>>(x, Wt, b_enc, nullptr, h, NN);

    for (int l = 0; l < NL; ++l) {
        if (l == 0)
            gemm128_mfma<1><<<gemmBlocks, 256, 0, stream>>>(
                h, Wt + (size_t)(l + 1) * 16384, nullptr, nullptr, t, NN);
        else
            gemm128_mfma<2><<<gemmBlocks, 256, 0, stream>>>(
                agg, Wt + (size_t)(l + 1) * 16384, nullptr, bnp, t, NN);
        aggregate_kernel<<<(NN + 3) / 4, 256, 0, stream>>>(t, rp, csr, dinv,
                                                           b + (size_t)l * HD, agg, NN);
        bn_stats_kernel<<<BN_BLOCKS, 512, 0, stream>>>(agg, partials, bncnt,
                                                       gamma + (size_t)l * HD,
                                                       beta + (size_t)l * HD, bnp, NN);
    }

    pool_cls_kernel<<<NB, 256, 0, stream>>>(agg, bnp, batch, W_cls, b_cls, out, NN);
}

// Round 8
// 413.514 us; speedup vs baseline: 2.0622x; 1.6417x over previous
//
#include <hip/hip_runtime.h>

#define NN 50000
#define NE 600000
#define HD 128
#define NL 4
#define NB 256
#define NO 10
#define BN_EPS 1e-5f

typedef short bf16x8 __attribute__((ext_vector_type(8)));
typedef float f32x4 __attribute__((ext_vector_type(4)));

__device__ __forceinline__ unsigned short f2bf(float f) {
    union { float f; unsigned int u; } x; x.f = f;
    unsigned int u = x.u;
    unsigned int r = (u + 0x7FFFu + ((u >> 16) & 1u)) >> 16;  // RNE
    return (unsigned short)r;
}
__device__ __forceinline__ float bf2f(unsigned short s) {
    union { unsigned int u; float f; } x; x.u = ((unsigned int)s) << 16;
    return x.f;
}

// ---------------- CSR build ----------------

__global__ void hist_kernel(const int* __restrict__ col, int* __restrict__ cnt, int e) {
    int i = blockIdx.x * blockDim.x + threadIdx.x;
    if (i < e) atomicAdd(&cnt[col[i]], 1);
}

// scan over M=N+1 elements + fused dinv
__global__ void scan1_kernel(const int* __restrict__ cnt, int* __restrict__ outp,
                             int* __restrict__ bsums, float* __restrict__ dinv,
                             int M, int n) {
    __shared__ int s[256];
    int tid = threadIdx.x;
    int base = blockIdx.x * 1024 + tid * 4;
    int v[4];
#pragma unroll
    for (int j = 0; j < 4; ++j) {
        int idx = base + j;
        v[j] = (idx < n) ? cnt[idx] : 0;
        if (idx < n) dinv[idx] = rsqrtf((float)(v[j] + 1));  // +1 self-loop
    }
    int tot = v[0] + v[1] + v[2] + v[3];
    s[tid] = tot;
    __syncthreads();
    for (int off = 1; off < 256; off <<= 1) {
        int x = (tid >= off) ? s[tid - off] : 0;
        __syncthreads();
        s[tid] += x;
        __syncthreads();
    }
    int run = (tid == 0) ? 0 : s[tid - 1];
#pragma unroll
    for (int j = 0; j < 4; ++j) {
        int idx = base + j;
        if (idx < M) outp[idx] = run;
        run += v[j];
    }
    if (tid == 255) bsums[blockIdx.x] = s[255];
}

__global__ void scan2_kernel(int* bsums, int nb) {
    if (threadIdx.x == 0 && blockIdx.x == 0) {
        int acc = 0;
        for (int i = 0; i < nb; ++i) { int v = bsums[i]; bsums[i] = acc; acc += v; }
    }
}

__global__ void scan3_kernel(int* __restrict__ outp, const int* __restrict__ bsums, int M) {
    int i = blockIdx.x * blockDim.x + threadIdx.x;
    if (i < M) outp[i] += bsums[i >> 10];
}

__global__ void place_kernel(const int* __restrict__ row, const int* __restrict__ col,
                             const float* __restrict__ dinv, const int* __restrict__ rp,
                             int* __restrict__ fill, int2* __restrict__ csr, int e) {
    int i = blockIdx.x * blockDim.x + threadIdx.x;
    if (i < e) {
        int r = row[i], c = col[i];
        int pos = atomicAdd(&fill[c], 1);
        int idx = rp[c] + pos;
        csr[idx] = make_int2(r, __float_as_int(dinv[r] * dinv[c]));
    }
}

// ---------------- weight transpose+convert: Wt[m][n][k] = bf16(Wsrc_m[k][n]) ----------------
__global__ void wconv_kernel(const float* __restrict__ W_enc, const float* __restrict__ W,
                             unsigned short* __restrict__ Wt) {
    int i = blockIdx.x * blockDim.x + threadIdx.x;
    if (i >= 5 * 16384) return;
    int m = i >> 14;
    int r = (i >> 7) & 127;  // dest row = n
    int k = i & 127;         // dest col = k
    const float* src = (m == 0) ? W_enc : (W + (size_t)(m - 1) * 16384);
    Wt[i] = f2bf(src[k * 128 + r]);
}

// ---------------- MFMA GEMM: C[n x 128] = A[n x 128] @ W[128 x 128] (+bias), C bf16 ----------------
// AMODE: 0 = fp32 A, 1 = bf16 A, 2 = fp32 A with fused BN(scale,shift)+ReLU
template <int AMODE>
__global__ __launch_bounds__(256) void gemm128_mfma(const void* __restrict__ Ap,
                                                    const unsigned short* __restrict__ Wt,
                                                    const float* __restrict__ bias,
                                                    const float* __restrict__ bnp,
                                                    unsigned short* __restrict__ Cp,
                                                    int nrows) {
    int wave = threadIdx.x >> 6;
    int lane = threadIdx.x & 63;
    int r16 = lane & 15;
    int kg = lane >> 4;
    int rowBase = blockIdx.x * 64 + wave * 16;
    int row = rowBase + r16;
    bool valid = row < nrows;

    bf16x8 afr[4];
#pragma unroll
    for (int s = 0; s < 4; ++s) {
        bf16x8 tt = {};
        int c0 = s * 32 + kg * 8;
        if constexpr (AMODE == 1) {
            const unsigned short* A = (const unsigned short*)Ap;
            if (valid) tt = *(const bf16x8*)&A[(size_t)row * 128 + c0];
        } else if constexpr (AMODE == 0) {
            const float* A = (const float*)Ap;
            if (valid) {
                const float* p = &A[(size_t)row * 128 + c0];
                float4 u0 = *(const float4*)p;
                float4 u1 = *(const float4*)(p + 4);
                tt[0] = (short)f2bf(u0.x); tt[1] = (short)f2bf(u0.y);
                tt[2] = (short)f2bf(u0.z); tt[3] = (short)f2bf(u0.w);
                tt[4] = (short)f2bf(u1.x); tt[5] = (short)f2bf(u1.y);
                tt[6] = (short)f2bf(u1.z); tt[7] = (short)f2bf(u1.w);
            }
        } else {
            const float* A = (const float*)Ap;
            if (valid) {
                const float* p = &A[(size_t)row * 128 + c0];
                float4 u0 = *(const float4*)p;
                float4 u1 = *(const float4*)(p + 4);
                float4 s0 = *(const float4*)&bnp[c0];
                float4 s1 = *(const float4*)&bnp[c0 + 4];
                float4 h0 = *(const float4*)&bnp[128 + c0];
                float4 h1 = *(const float4*)&bnp[128 + c0 + 4];
                tt[0] = (short)f2bf(fmaxf(u0.x * s0.x + h0.x, 0.f));
                tt[1] = (short)f2bf(fmaxf(u0.y * s0.y + h0.y, 0.f));
                tt[2] = (short)f2bf(fmaxf(u0.z * s0.z + h0.z, 0.f));
                tt[3] = (short)f2bf(fmaxf(u0.w * s0.w + h0.w, 0.f));
                tt[4] = (short)f2bf(fmaxf(u1.x * s1.x + h1.x, 0.f));
                tt[5] = (short)f2bf(fmaxf(u1.y * s1.y + h1.y, 0.f));
                tt[6] = (short)f2bf(fmaxf(u1.z * s1.z + h1.z, 0.f));
                tt[7] = (short)f2bf(fmaxf(u1.w * s1.w + h1.w, 0.f));
            }
        }
        afr[s] = tt;
    }

    f32x4 acc[8];
#pragma unroll
    for (int n = 0; n < 8; ++n) acc[n] = (f32x4){0.f, 0.f, 0.f, 0.f};

#pragma unroll
    for (int n = 0; n < 8; ++n) {
        const unsigned short* wp = &Wt[(size_t)(n * 16 + r16) * 128 + kg * 8];
#pragma unroll
        for (int s = 0; s < 4; ++s) {
            bf16x8 bfr = *(const bf16x8*)&wp[s * 32];
            acc[n] = __builtin_amdgcn_mfma_f32_16x16x32_bf16(afr[s], bfr, acc[n], 0, 0, 0);
        }
    }

    // C/D: lane holds rows kg*4+i, col r16 (within tile)
#pragma unroll
    for (int n = 0; n < 8; ++n) {
        int col = n * 16 + r16;
        float bv = bias ? bias[col] : 0.f;
#pragma unroll
        for (int i = 0; i < 4; ++i) {
            int orow = rowBase + kg * 4 + i;
            if (orow < nrows)
                Cp[(size_t)orow * 128 + col] = f2bf(acc[n][i] + bv);
        }
    }
}

// ---------------- Aggregation: agg[i] = b + dinv_i^2 * t[i] + sum_e w_e * t[src_e] ----------------
// One wave per node (max TLP for the latency-bound gather).
__global__ __launch_bounds__(256) void aggregate_kernel(const unsigned short* __restrict__ t,
                                                        const int* __restrict__ rp,
                                                        const int2* __restrict__ csr,
                                                        const float* __restrict__ dinv,
                                                        const float* __restrict__ bvec,
                                                        float* __restrict__ agg, int n) {
    int wid = blockIdx.x * 4 + (threadIdx.x >> 6);
    int lane = threadIdx.x & 63;
    if (wid >= n) return;
    int c = lane * 2;
    float di = dinv[wid];
    float sw = di * di;
    unsigned int u = *(const unsigned int*)&t[(size_t)wid * 128 + c];
    float2 acc;
    acc.x = sw * bf2f((unsigned short)(u & 0xffff)) + bvec[c];
    acc.y = sw * bf2f((unsigned short)(u >> 16)) + bvec[c + 1];
    int e = rp[wid], e1 = rp[wid + 1];
    for (; e + 3 < e1; e += 4) {
        int2 ew0 = csr[e], ew1 = csr[e + 1], ew2 = csr[e + 2], ew3 = csr[e + 3];
        unsigned int u0 = *(const unsigned int*)&t[(size_t)ew0.x * 128 + c];
        unsigned int u1 = *(const unsigned int*)&t[(size_t)ew1.x * 128 + c];
        unsigned int u2 = *(const unsigned int*)&t[(size_t)ew2.x * 128 + c];
        unsigned int u3 = *(const unsigned int*)&t[(size_t)ew3.x * 128 + c];
        float w0 = __int_as_float(ew0.y), w1 = __int_as_float(ew1.y);
        float w2 = __int_as_float(ew2.y), w3 = __int_as_float(ew3.y);
        acc.x += w0 * bf2f((unsigned short)(u0 & 0xffff)) + w1 * bf2f((unsigned short)(u1 & 0xffff));
        acc.y += w0 * bf2f((unsigned short)(u0 >> 16)) + w1 * bf2f((unsigned short)(u1 >> 16));
        acc.x += w2 * bf2f((unsigned short)(u2 & 0xffff)) + w3 * bf2f((unsigned short)(u3 & 0xffff));
        acc.y += w2 * bf2f((unsigned short)(u2 >> 16)) + w3 * bf2f((unsigned short)(u3 >> 16));
    }
    for (; e < e1; ++e) {
        int2 ew = csr[e];
        unsigned int u0 = *(const unsigned int*)&t[(size_t)ew.x * 128 + c];
        float w0 = __int_as_float(ew.y);
        acc.x += w0 * bf2f((unsigned short)(u0 & 0xffff));
        acc.y += w0 * bf2f((unsigned short)(u0 >> 16));
    }
    *(float2*)&agg[(size_t)wid * 128 + c] = acc;
}

// ---------------- BatchNorm stats: two kernels, NO fence / NO counter / NO atomics ----------------
// Stage 1: 256 blocks x 512 thr, f32x4 grid-stride; block-private 256-float partials, plain stores.
// Stage 2: one block reduces the 256KB partial buffer (L2-resident) and writes bnp.
#define BN_BLOCKS 256
__global__ __launch_bounds__(512) void bn_stats1_kernel(const float* __restrict__ agg,
                                                        float* __restrict__ partials, int n) {
    int tid = threadIdx.x;
    int c4 = tid & 31, rs = tid >> 5;  // 32 channel-quads x 16 row-streams
    f32x4 s = {0.f, 0.f, 0.f, 0.f}, q = {0.f, 0.f, 0.f, 0.f};
    for (int r = blockIdx.x * 16 + rs; r < n; r += BN_BLOCKS * 16) {
        f32x4 v = *(const f32x4*)&agg[(size_t)r * 128 + c4 * 4];
        s += v;
        q += v * v;
    }
    __shared__ f32x4 ls[512], lq[512];
    ls[tid] = s;
    lq[tid] = q;
    __syncthreads();
    if (tid < 32) {
        f32x4 ss = ls[tid], qq = lq[tid];
#pragma unroll
        for (int j = 1; j < 16; ++j) { ss += ls[tid + 32 * j]; qq += lq[tid + 32 * j]; }
        float* pb = partials + (size_t)blockIdx.x * 256;
        *(f32x4*)&pb[tid * 4] = ss;          // sums at [0,128)
        *(f32x4*)&pb[128 + tid * 4] = qq;    // sumsqs at [128,256)
    }
}

__global__ __launch_bounds__(256) void bn_stats2_kernel(const float* __restrict__ partials,
                                                        const float* __restrict__ gamma,
                                                        const float* __restrict__ beta,
                                                        float* __restrict__ bnp, float fn) {
    int tid = threadIdx.x;
    int col4 = tid & 63, g = tid >> 6;  // 64 f32x4-columns x 4 block-groups
    f32x4 acc = {0.f, 0.f, 0.f, 0.f};
#pragma unroll 8
    for (int bb = g; bb < BN_BLOCKS; bb += 4)
        acc += *(const f32x4*)&partials[(size_t)bb * 256 + col4 * 4];
    __shared__ f32x4 redv[256];
    __shared__ float red[256];
    redv[tid] = acc;
    __syncthreads();
    if (tid < 64) {
        f32x4 tot = redv[tid] + redv[tid + 64] + redv[tid + 128] + redv[tid + 192];
        *(f32x4*)&red[tid * 4] = tot;
    }
    __syncthreads();
    if (tid < 128) {
        float mean = red[tid] / fn;
        float var = fmaxf(red[128 + tid] / fn - mean * mean, 0.f);
        float sc = gamma[tid] * rsqrtf(var + BN_EPS);
        bnp[tid] = sc;
        bnp[128 + tid] = beta[tid] - mean * sc;
    }
}

// ---------------- Pool (BN+ReLU fused) + classifier, one block per graph ----------------
__global__ __launch_bounds__(256) void pool_cls_kernel(const float* __restrict__ agg,
                                                       const float* __restrict__ bnp,
                                                       const int* __restrict__ batch,
                                                       const float* __restrict__ Wc,
                                                       const float* __restrict__ bc,
                                                       float* __restrict__ out, int n) {
    int b = blockIdx.x;  // graph id, 0..NB-1
    int tid = threadIdx.x;
    // row range of graph b in sorted batch
    int lo = 0, hi = n;
    while (lo < hi) { int mid = (lo + hi) >> 1; if (batch[mid] < b) lo = mid + 1; else hi = mid; }
    int start = lo;
    hi = n;
    while (lo < hi) { int mid = (lo + hi) >> 1; if (batch[mid] <= b) lo = mid + 1; else hi = mid; }
    int end = lo;

    int c4 = tid & 31, rs = tid >> 5;
    f32x4 sc = *(const f32x4*)&bnp[c4 * 4];
    f32x4 sh = *(const f32x4*)&bnp[128 + c4 * 4];
    f32x4 acc = {0.f, 0.f, 0.f, 0.f};
    for (int r = start + rs; r < end; r += 8) {
        f32x4 v = *(const f32x4*)&agg[(size_t)r * 128 + c4 * 4];
        f32x4 y = v * sc + sh;
#pragma unroll
        for (int k = 0; k < 4; ++k) y[k] = fmaxf(y[k], 0.f);
        acc += y;
    }
    __shared__ f32x4 ls[256];
    __shared__ float g[128];
    ls[tid] = acc;
    __syncthreads();
    if (tid < 32) {
        f32x4 ss = ls[tid];
#pragma unroll
        for (int j = 1; j < 8; ++j) ss += ls[tid + 32 * j];
        float invc = 1.0f / fmaxf((float)(end - start), 1.0f);
#pragma unroll
        for (int k = 0; k < 4; ++k) g[tid * 4 + k] = ss[k] * invc;
    }
    __syncthreads();
    if (tid < NO) {
        float s = bc[tid];
        for (int c = 0; c < 128; ++c) s += g[c] * Wc[c * NO + tid];
        out[b * NO + tid] = s;
    }
}

// ---------------- host launch ----------------
extern "C" void kernel_launch(void* const* d_in, const int* in_sizes, int n_in,
                              void* d_out, int out_size, void* d_ws, size_t ws_size,
                              hipStream_t stream) {
    const float* x      = (const float*)d_in[0];
    const int*   eidx   = (const int*)d_in[1];
    const int*   batch  = (const int*)d_in[2];
    const float* W_enc  = (const float*)d_in[3];
    const float* b_enc  = (const float*)d_in[4];
    const float* W      = (const float*)d_in[5];
    const float* b      = (const float*)d_in[6];
    const float* gamma  = (const float*)d_in[7];
    const float* beta   = (const float*)d_in[8];
    const float* W_cls  = (const float*)d_in[9];
    const float* b_cls  = (const float*)d_in[10];
    float* out = (float*)d_out;

    const int* erow = eidx;
    const int* ecol = eidx + NE;

    // workspace layout
    float* agg      = (float*)d_ws;                      // NN*HD fp32
    float* dinv     = agg + (size_t)NN * HD;             // NN
    float* partials = dinv + NN;                         // BN_BLOCKS*256
    float* bnp      = partials + BN_BLOCKS * 256;        // 256
    int2*  csr      = (int2*)(bnp + 256);                // NE int2
    unsigned short* h  = (unsigned short*)(csr + NE);    // NN*HD bf16
    unsigned short* t  = h + (size_t)NN * HD;            // NN*HD bf16
    unsigned short* Wt = t + (size_t)NN * HD;            // 5*16384 bf16
    int* cnt      = (int*)(Wt + 5 * 16384);              // NN
    int* fill     = cnt + NN;                            // NN (adjacent -> one memset)
    int* rp       = fill + NN;                           // NN+1
    int* bsums    = rp + NN + 1;                         // 64

    hipMemsetAsync(cnt, 0, 2 * NN * sizeof(int), stream);

    // CSR build (once; reused across layers)
    hist_kernel<<<(NE + 255) / 256, 256, 0, stream>>>(ecol, cnt, NE);
    int M = NN + 1;
    int nscan = (M + 1023) / 1024;
    scan1_kernel<<<nscan, 256, 0, stream>>>(cnt, rp, bsums, dinv, M, NN);
    scan2_kernel<<<1, 64, 0, stream>>>(bsums, nscan);
    scan3_kernel<<<(M + 255) / 256, 256, 0, stream>>>(rp, bsums, M);
    place_kernel<<<(NE + 255) / 256, 256, 0, stream>>>(erow, ecol, dinv, rp, fill, csr, NE);

    // weights -> bf16 transposed
    wconv_kernel<<<(5 * 16384 + 255) / 256, 256, 0, stream>>>(W_enc, W, Wt);

    int gemmBlocks = (NN + 63) / 64;
    // encoder: x fp32 -> h bf16
    gemm128_mfma<0><<<gemmBlocks, 256, 0, stream>>>(x, Wt, b_enc, nullptr, h, NN);

    for (int l = 0; l < NL; ++l) {
        if (l == 0)
            gemm128_mfma<1><<<gemmBlocks, 256, 0, stream>>>(
                h, Wt + (size_t)(l + 1) * 16384, nullptr, nullptr, t, NN);
        else
            gemm128_mfma<2><<<gemmBlocks, 256, 0, stream>>>(
                agg, Wt + (size_t)(l + 1) * 16384, nullptr, bnp, t, NN);
        aggregate_kernel<<<(NN + 3) / 4, 256, 0, stream>>>(t, rp, csr, dinv,
                                                           b + (size_t)l * HD, agg, NN);
        bn_stats1_kernel<<<BN_BLOCKS, 512, 0, stream>>>(agg, partials, NN);
        bn_stats2_kernel<<<1, 256, 0, stream>>>(partials, gamma + (size_t)l * HD,
                                                beta + (size_t)l * HD, bnp, (float)NN);
    }

    pool_cls_kernel<<<NB, 256, 0, stream>>>(agg, bnp, batch, W_cls, b_cls, out, NN);
}

// Round 9
// 394.573 us; speedup vs baseline: 2.1612x; 1.0480x over previous
//
#include <hip/hip_runtime.h>

#define NN 50000
#define NE 600000
#define HD 128
#define NL 4
#define NB 256
#define NO 10
#define BN_EPS 1e-5f

typedef short bf16x8 __attribute__((ext_vector_type(8)));
typedef float f32x4 __attribute__((ext_vector_type(4)));

__device__ __forceinline__ unsigned short f2bf(float f) {
    union { float f; unsigned int u; } x; x.f = f;
    unsigned int u = x.u;
    unsigned int r = (u + 0x7FFFu + ((u >> 16) & 1u)) >> 16;  // RNE
    return (unsigned short)r;
}
__device__ __forceinline__ float bf2f(unsigned short s) {
    union { unsigned int u; float f; } x; x.u = ((unsigned int)s) << 16;
    return x.f;
}

// ---------------- CSR build ----------------

__global__ void hist_kernel(const int* __restrict__ col, int* __restrict__ cnt, int e) {
    int i = blockIdx.x * blockDim.x + threadIdx.x;
    if (i < e) atomicAdd(&cnt[col[i]], 1);
}

// scan over M=N+1 elements + fused dinv
__global__ void scan1_kernel(const int* __restrict__ cnt, int* __restrict__ outp,
                             int* __restrict__ bsums, float* __restrict__ dinv,
                             int M, int n) {
    __shared__ int s[256];
    int tid = threadIdx.x;
    int base = blockIdx.x * 1024 + tid * 4;
    int v[4];
#pragma unroll
    for (int j = 0; j < 4; ++j) {
        int idx = base + j;
        v[j] = (idx < n) ? cnt[idx] : 0;
        if (idx < n) dinv[idx] = rsqrtf((float)(v[j] + 1));  // +1 self-loop
    }
    int tot = v[0] + v[1] + v[2] + v[3];
    s[tid] = tot;
    __syncthreads();
    for (int off = 1; off < 256; off <<= 1) {
        int x = (tid >= off) ? s[tid - off] : 0;
        __syncthreads();
        s[tid] += x;
        __syncthreads();
    }
    int run = (tid == 0) ? 0 : s[tid - 1];
#pragma unroll
    for (int j = 0; j < 4; ++j) {
        int idx = base + j;
        if (idx < M) outp[idx] = run;
        run += v[j];
    }
    if (tid == 255) bsums[blockIdx.x] = s[255];
}

__global__ void scan2_kernel(int* bsums, int nb) {
    if (threadIdx.x == 0 && blockIdx.x == 0) {
        int acc = 0;
        for (int i = 0; i < nb; ++i) { int v = bsums[i]; bsums[i] = acc; acc += v; }
    }
}

__global__ void scan3_kernel(int* __restrict__ outp, const int* __restrict__ bsums, int M) {
    int i = blockIdx.x * blockDim.x + threadIdx.x;
    if (i < M) outp[i] += bsums[i >> 10];
}

__global__ void place_kernel(const int* __restrict__ row, const int* __restrict__ col,
                             const float* __restrict__ dinv, const int* __restrict__ rp,
                             int* __restrict__ fill, int2* __restrict__ csr, int e) {
    int i = blockIdx.x * blockDim.x + threadIdx.x;
    if (i < e) {
        int r = row[i], c = col[i];
        int pos = atomicAdd(&fill[c], 1);
        int idx = rp[c] + pos;
        csr[idx] = make_int2(r, __float_as_int(dinv[r] * dinv[c]));
    }
}

// ---------------- weight transpose+convert: Wt[m][n][k] = bf16(Wsrc_m[k][n]) ----------------
__global__ void wconv_kernel(const float* __restrict__ W_enc, const float* __restrict__ W,
                             unsigned short* __restrict__ Wt) {
    int i = blockIdx.x * blockDim.x + threadIdx.x;
    if (i >= 5 * 16384) return;
    int m = i >> 14;
    int r = (i >> 7) & 127;  // dest row = n
    int k = i & 127;         // dest col = k
    const float* src = (m == 0) ? W_enc : (W + (size_t)(m - 1) * 16384);
    Wt[i] = f2bf(src[k * 128 + r]);
}

// ---------------- MFMA GEMM: C[n x 128] = A[n x 128] @ W[128 x 128] (+bias), C bf16 ----------------
// AMODE: 0 = fp32 A, 1 = bf16 A, 2 = bf16 A with fused BN(scale,shift)+ReLU
template <int AMODE>
__global__ __launch_bounds__(256) void gemm128_mfma(const void* __restrict__ Ap,
                                                    const unsigned short* __restrict__ Wt,
                                                    const float* __restrict__ bias,
                                                    const float* __restrict__ bnp,
                                                    unsigned short* __restrict__ Cp,
                                                    int nrows) {
    int wave = threadIdx.x >> 6;
    int lane = threadIdx.x & 63;
    int r16 = lane & 15;
    int kg = lane >> 4;
    int rowBase = blockIdx.x * 64 + wave * 16;
    int row = rowBase + r16;
    bool valid = row < nrows;

    bf16x8 afr[4];
#pragma unroll
    for (int s = 0; s < 4; ++s) {
        bf16x8 tt = {};
        int c0 = s * 32 + kg * 8;
        if constexpr (AMODE == 1) {
            const unsigned short* A = (const unsigned short*)Ap;
            if (valid) tt = *(const bf16x8*)&A[(size_t)row * 128 + c0];
        } else if constexpr (AMODE == 0) {
            const float* A = (const float*)Ap;
            if (valid) {
                const float* p = &A[(size_t)row * 128 + c0];
                float4 u0 = *(const float4*)p;
                float4 u1 = *(const float4*)(p + 4);
                tt[0] = (short)f2bf(u0.x); tt[1] = (short)f2bf(u0.y);
                tt[2] = (short)f2bf(u0.z); tt[3] = (short)f2bf(u0.w);
                tt[4] = (short)f2bf(u1.x); tt[5] = (short)f2bf(u1.y);
                tt[6] = (short)f2bf(u1.z); tt[7] = (short)f2bf(u1.w);
            }
        } else {
            const unsigned short* A = (const unsigned short*)Ap;
            if (valid) {
                bf16x8 raw = *(const bf16x8*)&A[(size_t)row * 128 + c0];
                float4 s0 = *(const float4*)&bnp[c0];
                float4 s1 = *(const float4*)&bnp[c0 + 4];
                float4 h0 = *(const float4*)&bnp[128 + c0];
                float4 h1 = *(const float4*)&bnp[128 + c0 + 4];
                tt[0] = (short)f2bf(fmaxf(bf2f((unsigned short)raw[0]) * s0.x + h0.x, 0.f));
                tt[1] = (short)f2bf(fmaxf(bf2f((unsigned short)raw[1]) * s0.y + h0.y, 0.f));
                tt[2] = (short)f2bf(fmaxf(bf2f((unsigned short)raw[2]) * s0.z + h0.z, 0.f));
                tt[3] = (short)f2bf(fmaxf(bf2f((unsigned short)raw[3]) * s0.w + h0.w, 0.f));
                tt[4] = (short)f2bf(fmaxf(bf2f((unsigned short)raw[4]) * s1.x + h1.x, 0.f));
                tt[5] = (short)f2bf(fmaxf(bf2f((unsigned short)raw[5]) * s1.y + h1.y, 0.f));
                tt[6] = (short)f2bf(fmaxf(bf2f((unsigned short)raw[6]) * s1.z + h1.z, 0.f));
                tt[7] = (short)f2bf(fmaxf(bf2f((unsigned short)raw[7]) * s1.w + h1.w, 0.f));
            }
        }
        afr[s] = tt;
    }

    f32x4 acc[8];
#pragma unroll
    for (int n = 0; n < 8; ++n) acc[n] = (f32x4){0.f, 0.f, 0.f, 0.f};

#pragma unroll
    for (int n = 0; n < 8; ++n) {
        const unsigned short* wp = &Wt[(size_t)(n * 16 + r16) * 128 + kg * 8];
#pragma unroll
        for (int s = 0; s < 4; ++s) {
            bf16x8 bfr = *(const bf16x8*)&wp[s * 32];
            acc[n] = __builtin_amdgcn_mfma_f32_16x16x32_bf16(afr[s], bfr, acc[n], 0, 0, 0);
        }
    }

    // C/D: lane holds rows kg*4+i, col r16 (within tile)
#pragma unroll
    for (int n = 0; n < 8; ++n) {
        int col = n * 16 + r16;
        float bv = bias ? bias[col] : 0.f;
#pragma unroll
        for (int i = 0; i < 4; ++i) {
            int orow = rowBase + kg * 4 + i;
            if (orow < nrows)
                Cp[(size_t)orow * 128 + col] = f2bf(acc[n][i] + bv);
        }
    }
}

// ---------------- Aggregation: aggb[i] = bf16(b + dinv_i^2 * t[i] + sum_e w_e * t[src_e]) --------
// One wave per node (max TLP), 8 outstanding gather loads per round.
__global__ __launch_bounds__(256) void aggregate_kernel(const unsigned short* __restrict__ t,
                                                        const int* __restrict__ rp,
                                                        const int2* __restrict__ csr,
                                                        const float* __restrict__ dinv,
                                                        const float* __restrict__ bvec,
                                                        unsigned short* __restrict__ aggb, int n) {
    int wid = blockIdx.x * 4 + (threadIdx.x >> 6);
    int lane = threadIdx.x & 63;
    if (wid >= n) return;
    int c = lane * 2;
    float di = dinv[wid];
    float sw = di * di;
    unsigned int u = *(const unsigned int*)&t[(size_t)wid * 128 + c];
    float ax = sw * bf2f((unsigned short)(u & 0xffff)) + bvec[c];
    float ay = sw * bf2f((unsigned short)(u >> 16)) + bvec[c + 1];
    int e = rp[wid], e1 = rp[wid + 1];
    for (; e + 7 < e1; e += 8) {
        int2 ew[8];
        unsigned int uu[8];
#pragma unroll
        for (int j = 0; j < 8; ++j) ew[j] = csr[e + j];
#pragma unroll
        for (int j = 0; j < 8; ++j) uu[j] = *(const unsigned int*)&t[(size_t)ew[j].x * 128 + c];
#pragma unroll
        for (int j = 0; j < 8; ++j) {
            float w = __int_as_float(ew[j].y);
            ax += w * bf2f((unsigned short)(uu[j] & 0xffff));
            ay += w * bf2f((unsigned short)(uu[j] >> 16));
        }
    }
    for (; e + 3 < e1; e += 4) {
        int2 ew[4];
        unsigned int uu[4];
#pragma unroll
        for (int j = 0; j < 4; ++j) ew[j] = csr[e + j];
#pragma unroll
        for (int j = 0; j < 4; ++j) uu[j] = *(const unsigned int*)&t[(size_t)ew[j].x * 128 + c];
#pragma unroll
        for (int j = 0; j < 4; ++j) {
            float w = __int_as_float(ew[j].y);
            ax += w * bf2f((unsigned short)(uu[j] & 0xffff));
            ay += w * bf2f((unsigned short)(uu[j] >> 16));
        }
    }
    for (; e < e1; ++e) {
        int2 ew = csr[e];
        unsigned int u0 = *(const unsigned int*)&t[(size_t)ew.x * 128 + c];
        float w0 = __int_as_float(ew.y);
        ax += w0 * bf2f((unsigned short)(u0 & 0xffff));
        ay += w0 * bf2f((unsigned short)(u0 >> 16));
    }
    unsigned int o = (unsigned int)f2bf(ax) | ((unsigned int)f2bf(ay) << 16);
    *(unsigned int*)&aggb[(size_t)wid * 128 + c] = o;
}

// ---------------- BatchNorm stats: two kernels, NO fence / NO counter / NO atomics ----------------
#define BN_BLOCKS 256
__global__ __launch_bounds__(512) void bn_stats1_kernel(const unsigned short* __restrict__ aggb,
                                                        float* __restrict__ partials, int n) {
    int tid = threadIdx.x;
    int c4 = tid & 31, rs = tid >> 5;  // 32 channel-quads x 16 row-streams
    f32x4 s = {0.f, 0.f, 0.f, 0.f}, q = {0.f, 0.f, 0.f, 0.f};
    for (int r = blockIdx.x * 16 + rs; r < n; r += BN_BLOCKS * 16) {
        ushort4 v4 = *(const ushort4*)&aggb[(size_t)r * 128 + c4 * 4];
        f32x4 v = {bf2f(v4.x), bf2f(v4.y), bf2f(v4.z), bf2f(v4.w)};
        s += v;
        q += v * v;
    }
    __shared__ f32x4 ls[512], lq[512];
    ls[tid] = s;
    lq[tid] = q;
    __syncthreads();
    if (tid < 32) {
        f32x4 ss = ls[tid], qq = lq[tid];
#pragma unroll
        for (int j = 1; j < 16; ++j) { ss += ls[tid + 32 * j]; qq += lq[tid + 32 * j]; }
        float* pb = partials + (size_t)blockIdx.x * 256;
        *(f32x4*)&pb[tid * 4] = ss;          // sums at [0,128)
        *(f32x4*)&pb[128 + tid * 4] = qq;    // sumsqs at [128,256)
    }
}

__global__ __launch_bounds__(256) void bn_stats2_kernel(const float* __restrict__ partials,
                                                        const float* __restrict__ gamma,
                                                        const float* __restrict__ beta,
                                                        float* __restrict__ bnp, float fn) {
    int tid = threadIdx.x;
    int col4 = tid & 63, g = tid >> 6;  // 64 f32x4-columns x 4 block-groups
    f32x4 acc = {0.f, 0.f, 0.f, 0.f};
#pragma unroll 8
    for (int bb = g; bb < BN_BLOCKS; bb += 4)
        acc += *(const f32x4*)&partials[(size_t)bb * 256 + col4 * 4];
    __shared__ f32x4 redv[256];
    __shared__ float red[256];
    redv[tid] = acc;
    __syncthreads();
    if (tid < 64) {
        f32x4 tot = redv[tid] + redv[tid + 64] + redv[tid + 128] + redv[tid + 192];
        *(f32x4*)&red[tid * 4] = tot;
    }
    __syncthreads();
    if (tid < 128) {
        float mean = red[tid] / fn;
        float var = fmaxf(red[128 + tid] / fn - mean * mean, 0.f);
        float sc = gamma[tid] * rsqrtf(var + BN_EPS);
        bnp[tid] = sc;
        bnp[128 + tid] = beta[tid] - mean * sc;
    }
}

// ---------------- Pool (BN+ReLU fused) + classifier, one block per graph ----------------
__global__ __launch_bounds__(256) void pool_cls_kernel(const unsigned short* __restrict__ aggb,
                                                       const float* __restrict__ bnp,
                                                       const int* __restrict__ batch,
                                                       const float* __restrict__ Wc,
                                                       const float* __restrict__ bc,
                                                       float* __restrict__ out, int n) {
    int b = blockIdx.x;  // graph id, 0..NB-1
    int tid = threadIdx.x;
    // row range of graph b in sorted batch
    int lo = 0, hi = n;
    while (lo < hi) { int mid = (lo + hi) >> 1; if (batch[mid] < b) lo = mid + 1; else hi = mid; }
    int start = lo;
    hi = n;
    while (lo < hi) { int mid = (lo + hi) >> 1; if (batch[mid] <= b) lo = mid + 1; else hi = mid; }
    int end = lo;

    int c4 = tid & 31, rs = tid >> 5;
    f32x4 sc = *(const f32x4*)&bnp[c4 * 4];
    f32x4 sh = *(const f32x4*)&bnp[128 + c4 * 4];
    f32x4 acc = {0.f, 0.f, 0.f, 0.f};
    for (int r = start + rs; r < end; r += 8) {
        ushort4 v4 = *(const ushort4*)&aggb[(size_t)r * 128 + c4 * 4];
        f32x4 v = {bf2f(v4.x), bf2f(v4.y), bf2f(v4.z), bf2f(v4.w)};
        f32x4 y = v * sc + sh;
#pragma unroll
        for (int k = 0; k < 4; ++k) y[k] = fmaxf(y[k], 0.f);
        acc += y;
    }
    __shared__ f32x4 ls[256];
    __shared__ float g[128];
    ls[tid] = acc;
    __syncthreads();
    if (tid < 32) {
        f32x4 ss = ls[tid];
#pragma unroll
        for (int j = 1; j < 8; ++j) ss += ls[tid + 32 * j];
        float invc = 1.0f / fmaxf((float)(end - start), 1.0f);
#pragma unroll
        for (int k = 0; k < 4; ++k) g[tid * 4 + k] = ss[k] * invc;
    }
    __syncthreads();
    if (tid < NO) {
        float s = bc[tid];
        for (int c = 0; c < 128; ++c) s += g[c] * Wc[c * NO + tid];
        out[b * NO + tid] = s;
    }
}

// ---------------- host launch ----------------
extern "C" void kernel_launch(void* const* d_in, const int* in_sizes, int n_in,
                              void* d_out, int out_size, void* d_ws, size_t ws_size,
                              hipStream_t stream) {
    const float* x      = (const float*)d_in[0];
    const int*   eidx   = (const int*)d_in[1];
    const int*   batch  = (const int*)d_in[2];
    const float* W_enc  = (const float*)d_in[3];
    const float* b_enc  = (const float*)d_in[4];
    const float* W      = (const float*)d_in[5];
    const float* b      = (const float*)d_in[6];
    const float* gamma  = (const float*)d_in[7];
    const float* beta   = (const float*)d_in[8];
    const float* W_cls  = (const float*)d_in[9];
    const float* b_cls  = (const float*)d_in[10];
    float* out = (float*)d_out;

    const int* erow = eidx;
    const int* ecol = eidx + NE;

    // workspace layout
    float* dinv     = (float*)d_ws;                      // NN
    float* partials = dinv + NN;                         // BN_BLOCKS*256
    float* bnp      = partials + BN_BLOCKS * 256;        // 256
    int2*  csr      = (int2*)(bnp + 256);                // NE int2
    unsigned short* h    = (unsigned short*)(csr + NE);  // NN*HD bf16
    unsigned short* t    = h + (size_t)NN * HD;          // NN*HD bf16
    unsigned short* aggb = t + (size_t)NN * HD;          // NN*HD bf16
    unsigned short* Wt   = aggb + (size_t)NN * HD;       // 5*16384 bf16
    int* cnt      = (int*)(Wt + 5 * 16384);              // NN
    int* fill     = cnt + NN;                            // NN (adjacent -> one memset)
    int* rp       = fill + NN;                           // NN+1
    int* bsums    = rp + NN + 1;                         // 64

    hipMemsetAsync(cnt, 0, 2 * NN * sizeof(int), stream);

    // CSR build (once; reused across layers)
    hist_kernel<<<(NE + 255) / 256, 256, 0, stream>>>(ecol, cnt, NE);
    int M = NN + 1;
    int nscan = (M + 1023) / 1024;
    scan1_kernel<<<nscan, 256, 0, stream>>>(cnt, rp, bsums, dinv, M, NN);
    scan2_kernel<<<1, 64, 0, stream>>>(bsums, nscan);
    scan3_kernel<<<(M + 255) / 256, 256, 0, stream>>>(rp, bsums, M);
    place_kernel<<<(NE + 255) / 256, 256, 0, stream>>>(erow, ecol, dinv, rp, fill, csr, NE);

    // weights -> bf16 transposed
    wconv_kernel<<<(5 * 16384 + 255) / 256, 256, 0, stream>>>(W_enc, W, Wt);

    int gemmBlocks = (NN + 63) / 64;
    // encoder: x fp32 -> h bf16
    gemm128_mfma<0><<<gemmBlocks, 256, 0, stream>>>(x, Wt, b_enc, nullptr, h, NN);

    for (int l = 0; l < NL; ++l) {
        if (l == 0)
            gemm128_mfma<1><<<gemmBlocks, 256, 0, stream>>>(
                h, Wt + (size_t)(l + 1) * 16384, nullptr, nullptr, t, NN);
        else
            gemm128_mfma<2><<<gemmBlocks, 256, 0, stream>>>(
                aggb, Wt + (size_t)(l + 1) * 16384, nullptr, bnp, t, NN);
        aggregate_kernel<<<(NN + 3) / 4, 256, 0, stream>>>(t, rp, csr, dinv,
                                                           b + (size_t)l * HD, aggb, NN);
        bn_stats1_kernel<<<BN_BLOCKS, 512, 0, stream>>>(aggb, partials, NN);
        bn_stats2_kernel<<<1, 256, 0, stream>>>(partials, gamma + (size_t)l * HD,
                                                beta + (size_t)l * HD, bnp, (float)NN);
    }

    pool_cls_kernel<<<NB, 256, 0, stream>>>(aggb, bnp, batch, W_cls, b_cls, out, NN);
}

// Round 10
// 368.051 us; speedup vs baseline: 2.3170x; 1.0721x over previous
//
#include <hip/hip_runtime.h>

#define NN 50000
#define NE 600000
#define HD 128
#define NL 4
#define NB 256
#define NO 10
#define BN_EPS 1e-5f

typedef short bf16x8 __attribute__((ext_vector_type(8)));
typedef float f32x4 __attribute__((ext_vector_type(4)));

__device__ __forceinline__ unsigned short f2bf(float f) {
    union { float f; unsigned int u; } x; x.f = f;
    unsigned int u = x.u;
    unsigned int r = (u + 0x7FFFu + ((u >> 16) & 1u)) >> 16;  // RNE
    return (unsigned short)r;
}
__device__ __forceinline__ float bf2f(unsigned short s) {
    union { unsigned int u; float f; } x; x.u = ((unsigned int)s) << 16;
    return x.f;
}

// ---------------- CSR build ----------------

__global__ void hist_kernel(const int* __restrict__ col, int* __restrict__ cnt, int e) {
    int i = blockIdx.x * blockDim.x + threadIdx.x;
    if (i < e) atomicAdd(&cnt[col[i]], 1);
}

// scan over M=N+1 elements + fused dinv
__global__ void scan1_kernel(const int* __restrict__ cnt, int* __restrict__ outp,
                             int* __restrict__ bsums, float* __restrict__ dinv,
                             int M, int n) {
    __shared__ int s[256];
    int tid = threadIdx.x;
    int base = blockIdx.x * 1024 + tid * 4;
    int v[4];
#pragma unroll
    for (int j = 0; j < 4; ++j) {
        int idx = base + j;
        v[j] = (idx < n) ? cnt[idx] : 0;
        if (idx < n) dinv[idx] = rsqrtf((float)(v[j] + 1));  // +1 self-loop
    }
    int tot = v[0] + v[1] + v[2] + v[3];
    s[tid] = tot;
    __syncthreads();
    for (int off = 1; off < 256; off <<= 1) {
        int x = (tid >= off) ? s[tid - off] : 0;
        __syncthreads();
        s[tid] += x;
        __syncthreads();
    }
    int run = (tid == 0) ? 0 : s[tid - 1];
#pragma unroll
    for (int j = 0; j < 4; ++j) {
        int idx = base + j;
        if (idx < M) outp[idx] = run;
        run += v[j];
    }
    if (tid == 255) bsums[blockIdx.x] = s[255];
}

// scan3 with fused block-sum prefix (replaces scan2): each block reduces bsums[0..seg)
__global__ void scan3_kernel(int* __restrict__ outp, const int* __restrict__ bsums, int M) {
    __shared__ int sb[64];
    int tid = threadIdx.x;
    int seg = blockIdx.x >> 2;  // 256-thread block lies inside one 1024-wide segment
    if (tid < 64) sb[tid] = (tid < seg) ? bsums[tid] : 0;
    __syncthreads();
    if (tid < 32) sb[tid] += sb[tid + 32];
    __syncthreads();
    if (tid < 16) sb[tid] += sb[tid + 16];
    __syncthreads();
    if (tid < 8) sb[tid] += sb[tid + 8];
    __syncthreads();
    if (tid < 4) sb[tid] += sb[tid + 4];
    __syncthreads();
    if (tid < 2) sb[tid] += sb[tid + 2];
    __syncthreads();
    if (tid == 0) sb[0] += sb[1];
    __syncthreads();
    int i = blockIdx.x * 256 + tid;
    if (i < M) outp[i] += sb[0];
}

__global__ void place_kernel(const int* __restrict__ row, const int* __restrict__ col,
                             const float* __restrict__ dinv, const int* __restrict__ rp,
                             int* __restrict__ fill, int2* __restrict__ csr, int e) {
    int i = blockIdx.x * blockDim.x + threadIdx.x;
    if (i < e) {
        int r = row[i], c = col[i];
        int pos = atomicAdd(&fill[c], 1);
        int idx = rp[c] + pos;
        csr[idx] = make_int2(r, __float_as_int(dinv[r] * dinv[c]));
    }
}

// ---------------- weight transpose+convert for layers 1..4: Wt[m][n][k] = bf16(W[m-1][k][n]) ----
__global__ void wconv_kernel(const float* __restrict__ W, unsigned short* __restrict__ Wt) {
    int i = blockIdx.x * blockDim.x + threadIdx.x;
    if (i >= 4 * 16384) return;
    int m = i >> 14;              // 0..3 -> slot m+1
    int r = (i >> 7) & 127;       // dest row = n (out channel)
    int k = i & 127;              // dest col = k
    Wt[16384 + i] = f2bf(W[(size_t)m * 16384 + k * 128 + r]);
}

// ---------------- encoder folding: WtK[o][i] = bf16(sum_h W_enc[i][h] W0[h][o]); bb = b_enc@W0 ----
__global__ void fuse_enc_kernel(const float* __restrict__ W_enc, const float* __restrict__ W0,
                                const float* __restrict__ b_enc,
                                unsigned short* __restrict__ WtK, float* __restrict__ bb) {
    if (blockIdx.x < 64) {
        int gid = blockIdx.x * 256 + threadIdx.x;
        int i = gid & 127, o = gid >> 7;
        float s = 0.f;
#pragma unroll 8
        for (int h = 0; h < 128; ++h) s += W_enc[i * 128 + h] * W0[h * 128 + o];
        WtK[o * 128 + i] = f2bf(s);
    } else if (threadIdx.x < 128) {
        int o = threadIdx.x;
        float s = 0.f;
#pragma unroll 8
        for (int h = 0; h < 128; ++h) s += b_enc[h] * W0[h * 128 + o];
        bb[o] = s;
    }
}

// ---------------- MFMA GEMM: C[n x 128] = A[n x 128] @ W[128 x 128] (+bias), C bf16 ----------------
// Operand-swapped: W fragment as MFMA A-operand, node fragment as B-operand, so
// D col = node (= r16, the row this lane loaded) and D row = 4 consecutive out-channels
// -> epilogue is 8 packed 8B stores instead of 32 scattered 4B stores.
// AMODE: 0 = fp32 A, 1 = bf16 A, 2 = bf16 A with fused BN(scale,shift)+ReLU
template <int AMODE>
__global__ __launch_bounds__(256) void gemm128_mfma(const void* __restrict__ Ap,
                                                    const unsigned short* __restrict__ Wt,
                                                    const float* __restrict__ bias,
                                                    const float* __restrict__ bnp,
                                                    unsigned short* __restrict__ Cp,
                                                    int nrows) {
    int wave = threadIdx.x >> 6;
    int lane = threadIdx.x & 63;
    int r16 = lane & 15;
    int kg = lane >> 4;
    int rowBase = blockIdx.x * 64 + wave * 16;
    int row = rowBase + r16;
    bool valid = row < nrows;

    bf16x8 afr[4];  // node data = MFMA B operand (col = r16)
#pragma unroll
    for (int s = 0; s < 4; ++s) {
        bf16x8 tt = {};
        int c0 = s * 32 + kg * 8;
        if constexpr (AMODE == 1) {
            const unsigned short* A = (const unsigned short*)Ap;
            if (valid) tt = *(const bf16x8*)&A[(size_t)row * 128 + c0];
        } else if constexpr (AMODE == 0) {
            const float* A = (const float*)Ap;
            if (valid) {
                const float* p = &A[(size_t)row * 128 + c0];
                float4 u0 = *(const float4*)p;
                float4 u1 = *(const float4*)(p + 4);
                tt[0] = (short)f2bf(u0.x); tt[1] = (short)f2bf(u0.y);
                tt[2] = (short)f2bf(u0.z); tt[3] = (short)f2bf(u0.w);
                tt[4] = (short)f2bf(u1.x); tt[5] = (short)f2bf(u1.y);
                tt[6] = (short)f2bf(u1.z); tt[7] = (short)f2bf(u1.w);
            }
        } else {
            const unsigned short* A = (const unsigned short*)Ap;
            if (valid) {
                bf16x8 raw = *(const bf16x8*)&A[(size_t)row * 128 + c0];
                float4 s0 = *(const float4*)&bnp[c0];
                float4 s1 = *(const float4*)&bnp[c0 + 4];
                float4 h0 = *(const float4*)&bnp[128 + c0];
                float4 h1 = *(const float4*)&bnp[128 + c0 + 4];
                tt[0] = (short)f2bf(fmaxf(bf2f((unsigned short)raw[0]) * s0.x + h0.x, 0.f));
                tt[1] = (short)f2bf(fmaxf(bf2f((unsigned short)raw[1]) * s0.y + h0.y, 0.f));
                tt[2] = (short)f2bf(fmaxf(bf2f((unsigned short)raw[2]) * s0.z + h0.z, 0.f));
                tt[3] = (short)f2bf(fmaxf(bf2f((unsigned short)raw[3]) * s0.w + h0.w, 0.f));
                tt[4] = (short)f2bf(fmaxf(bf2f((unsigned short)raw[4]) * s1.x + h1.x, 0.f));
                tt[5] = (short)f2bf(fmaxf(bf2f((unsigned short)raw[5]) * s1.y + h1.y, 0.f));
                tt[6] = (short)f2bf(fmaxf(bf2f((unsigned short)raw[6]) * s1.z + h1.z, 0.f));
                tt[7] = (short)f2bf(fmaxf(bf2f((unsigned short)raw[7]) * s1.w + h1.w, 0.f));
            }
        }
        afr[s] = tt;
    }

    f32x4 acc[8];
#pragma unroll
    for (int n = 0; n < 8; ++n) acc[n] = (f32x4){0.f, 0.f, 0.f, 0.f};

#pragma unroll
    for (int n = 0; n < 8; ++n) {
        const unsigned short* wp = &Wt[(size_t)(n * 16 + r16) * 128 + kg * 8];
#pragma unroll
        for (int s = 0; s < 4; ++s) {
            bf16x8 wfr = *(const bf16x8*)&wp[s * 32];  // W = MFMA A operand (row = r16)
            acc[n] = __builtin_amdgcn_mfma_f32_16x16x32_bf16(wfr, afr[s], acc[n], 0, 0, 0);
        }
    }

    // D: col = r16 (node), row = kg*4+i (out channel) -> 4 consecutive cols per fragment
    if (valid) {
#pragma unroll
        for (int n = 0; n < 8; ++n) {
            int cbase = n * 16 + kg * 4;
            float4 bv = make_float4(0.f, 0.f, 0.f, 0.f);
            if (bias) bv = *(const float4*)&bias[cbase];
            ushort4 o;
            o.x = f2bf(acc[n][0] + bv.x);
            o.y = f2bf(acc[n][1] + bv.y);
            o.z = f2bf(acc[n][2] + bv.z);
            o.w = f2bf(acc[n][3] + bv.w);
            *(ushort4*)&Cp[(size_t)row * 128 + cbase] = o;
        }
    }
}

// ---------------- Aggregation: aggb[i] = bf16(b + dinv_i^2 * t[i] + sum_e w_e * t[src_e]) --------
// One wave per node (max TLP), 8 outstanding gather loads per round.
__global__ __launch_bounds__(256) void aggregate_kernel(const unsigned short* __restrict__ t,
                                                        const int* __restrict__ rp,
                                                        const int2* __restrict__ csr,
                                                        const float* __restrict__ dinv,
                                                        const float* __restrict__ bvec,
                                                        unsigned short* __restrict__ aggb, int n) {
    int wid = blockIdx.x * 4 + (threadIdx.x >> 6);
    int lane = threadIdx.x & 63;
    if (wid >= n) return;
    int c = lane * 2;
    float di = dinv[wid];
    float sw = di * di;
    unsigned int u = *(const unsigned int*)&t[(size_t)wid * 128 + c];
    float ax = sw * bf2f((unsigned short)(u & 0xffff)) + bvec[c];
    float ay = sw * bf2f((unsigned short)(u >> 16)) + bvec[c + 1];
    int e = rp[wid], e1 = rp[wid + 1];
    for (; e + 7 < e1; e += 8) {
        int2 ew[8];
        unsigned int uu[8];
#pragma unroll
        for (int j = 0; j < 8; ++j) ew[j] = csr[e + j];
#pragma unroll
        for (int j = 0; j < 8; ++j) uu[j] = *(const unsigned int*)&t[(size_t)ew[j].x * 128 + c];
#pragma unroll
        for (int j = 0; j < 8; ++j) {
            float w = __int_as_float(ew[j].y);
            ax += w * bf2f((unsigned short)(uu[j] & 0xffff));
            ay += w * bf2f((unsigned short)(uu[j] >> 16));
        }
    }
    for (; e + 3 < e1; e += 4) {
        int2 ew[4];
        unsigned int uu[4];
#pragma unroll
        for (int j = 0; j < 4; ++j) ew[j] = csr[e + j];
#pragma unroll
        for (int j = 0; j < 4; ++j) uu[j] = *(const unsigned int*)&t[(size_t)ew[j].x * 128 + c];
#pragma unroll
        for (int j = 0; j < 4; ++j) {
            float w = __int_as_float(ew[j].y);
            ax += w * bf2f((unsigned short)(uu[j] & 0xffff));
            ay += w * bf2f((unsigned short)(uu[j] >> 16));
        }
    }
    for (; e < e1; ++e) {
        int2 ew = csr[e];
        unsigned int u0 = *(const unsigned int*)&t[(size_t)ew.x * 128 + c];
        float w0 = __int_as_float(ew.y);
        ax += w0 * bf2f((unsigned short)(u0 & 0xffff));
        ay += w0 * bf2f((unsigned short)(u0 >> 16));
    }
    unsigned int o = (unsigned int)f2bf(ax) | ((unsigned int)f2bf(ay) << 16);
    *(unsigned int*)&aggb[(size_t)wid * 128 + c] = o;
}

// ---------------- BatchNorm stats: two kernels, NO fence / NO counter / NO atomics ----------------
#define BN_BLOCKS 256
__global__ __launch_bounds__(512) void bn_stats1_kernel(const unsigned short* __restrict__ aggb,
                                                        float* __restrict__ partials, int n) {
    int tid = threadIdx.x;
    int c4 = tid & 31, rs = tid >> 5;  // 32 channel-quads x 16 row-streams
    f32x4 s = {0.f, 0.f, 0.f, 0.f}, q = {0.f, 0.f, 0.f, 0.f};
    for (int r = blockIdx.x * 16 + rs; r < n; r += BN_BLOCKS * 16) {
        ushort4 v4 = *(const ushort4*)&aggb[(size_t)r * 128 + c4 * 4];
        f32x4 v = {bf2f(v4.x), bf2f(v4.y), bf2f(v4.z), bf2f(v4.w)};
        s += v;
        q += v * v;
    }
    __shared__ f32x4 ls[512], lq[512];
    ls[tid] = s;
    lq[tid] = q;
    __syncthreads();
    if (tid < 32) {
        f32x4 ss = ls[tid], qq = lq[tid];
#pragma unroll
        for (int j = 1; j < 16; ++j) { ss += ls[tid + 32 * j]; qq += lq[tid + 32 * j]; }
        float* pb = partials + (size_t)blockIdx.x * 256;
        *(f32x4*)&pb[tid * 4] = ss;          // sums at [0,128)
        *(f32x4*)&pb[128 + tid * 4] = qq;    // sumsqs at [128,256)
    }
}

__global__ __launch_bounds__(256) void bn_stats2_kernel(const float* __restrict__ partials,
                                                        const float* __restrict__ gamma,
                                                        const float* __restrict__ beta,
                                                        float* __restrict__ bnp, float fn) {
    int tid = threadIdx.x;
    int col4 = tid & 63, g = tid >> 6;  // 64 f32x4-columns x 4 block-groups
    f32x4 acc = {0.f, 0.f, 0.f, 0.f};
#pragma unroll 8
    for (int bb = g; bb < BN_BLOCKS; bb += 4)
        acc += *(const f32x4*)&partials[(size_t)bb * 256 + col4 * 4];
    __shared__ f32x4 redv[256];
    __shared__ float red[256];
    redv[tid] = acc;
    __syncthreads();
    if (tid < 64) {
        f32x4 tot = redv[tid] + redv[tid + 64] + redv[tid + 128] + redv[tid + 192];
        *(f32x4*)&red[tid * 4] = tot;
    }
    __syncthreads();
    if (tid < 128) {
        float mean = red[tid] / fn;
        float var = fmaxf(red[128 + tid] / fn - mean * mean, 0.f);
        float sc = gamma[tid] * rsqrtf(var + BN_EPS);
        bnp[tid] = sc;
        bnp[128 + tid] = beta[tid] - mean * sc;
    }
}

// ---------------- Pool (BN+ReLU fused) + classifier, one block per graph ----------------
__global__ __launch_bounds__(256) void pool_cls_kernel(const unsigned short* __restrict__ aggb,
                                                       const float* __restrict__ bnp,
                                                       const int* __restrict__ batch,
                                                       const float* __restrict__ Wc,
                                                       const float* __restrict__ bc,
                                                       float* __restrict__ out, int n) {
    int b = blockIdx.x;  // graph id, 0..NB-1
    int tid = threadIdx.x;
    // row range of graph b in sorted batch
    int lo = 0, hi = n;
    while (lo < hi) { int mid = (lo + hi) >> 1; if (batch[mid] < b) lo = mid + 1; else hi = mid; }
    int start = lo;
    hi = n;
    while (lo < hi) { int mid = (lo + hi) >> 1; if (batch[mid] <= b) lo = mid + 1; else hi = mid; }
    int end = lo;

    int c4 = tid & 31, rs = tid >> 5;
    f32x4 sc = *(const f32x4*)&bnp[c4 * 4];
    f32x4 sh = *(const f32x4*)&bnp[128 + c4 * 4];
    f32x4 acc = {0.f, 0.f, 0.f, 0.f};
    for (int r = start + rs; r < end; r += 8) {
        ushort4 v4 = *(const ushort4*)&aggb[(size_t)r * 128 + c4 * 4];
        f32x4 v = {bf2f(v4.x), bf2f(v4.y), bf2f(v4.z), bf2f(v4.w)};
        f32x4 y = v * sc + sh;
#pragma unroll
        for (int k = 0; k < 4; ++k) y[k] = fmaxf(y[k], 0.f);
        acc += y;
    }
    __shared__ f32x4 ls[256];
    __shared__ float g[128];
    ls[tid] = acc;
    __syncthreads();
    if (tid < 32) {
        f32x4 ss = ls[tid];
#pragma unroll
        for (int j = 1; j < 8; ++j) ss += ls[tid + 32 * j];
        float invc = 1.0f / fmaxf((float)(end - start), 1.0f);
#pragma unroll
        for (int k = 0; k < 4; ++k) g[tid * 4 + k] = ss[k] * invc;
    }
    __syncthreads();
    if (tid < NO) {
        float s = bc[tid];
        for (int c = 0; c < 128; ++c) s += g[c] * Wc[c * NO + tid];
        out[b * NO + tid] = s;
    }
}

// ---------------- host launch ----------------
extern "C" void kernel_launch(void* const* d_in, const int* in_sizes, int n_in,
                              void* d_out, int out_size, void* d_ws, size_t ws_size,
                              hipStream_t stream) {
    const float* x      = (const float*)d_in[0];
    const int*   eidx   = (const int*)d_in[1];
    const int*   batch  = (const int*)d_in[2];
    const float* W_enc  = (const float*)d_in[3];
    const float* b_enc  = (const float*)d_in[4];
    const float* W      = (const float*)d_in[5];
    const float* b      = (const float*)d_in[6];
    const float* gamma  = (const float*)d_in[7];
    const float* beta   = (const float*)d_in[8];
    const float* W_cls  = (const float*)d_in[9];
    const float* b_cls  = (const float*)d_in[10];
    float* out = (float*)d_out;

    const int* erow = eidx;
    const int* ecol = eidx + NE;

    // workspace layout
    float* dinv     = (float*)d_ws;                      // NN
    float* partials = dinv + NN;                         // BN_BLOCKS*256
    float* bnp      = partials + BN_BLOCKS * 256;        // 256
    float* bb       = bnp + 256;                         // 128 (fused encoder bias)
    int2*  csr      = (int2*)(bb + 128);                 // NE int2
    unsigned short* t    = (unsigned short*)(csr + NE);  // NN*HD bf16
    unsigned short* aggb = t + (size_t)NN * HD;          // NN*HD bf16
    unsigned short* Wt   = aggb + (size_t)NN * HD;       // 5*16384 bf16 (slot0 = fused enc)
    int* cnt      = (int*)(Wt + 5 * 16384);              // NN
    int* fill     = cnt + NN;                            // NN (adjacent -> one memset)
    int* rp       = fill + NN;                           // NN+1
    int* bsums    = rp + NN + 1;                         // 64

    hipMemsetAsync(cnt, 0, 2 * NN * sizeof(int), stream);

    // CSR build (once; reused across layers)
    hist_kernel<<<(NE + 255) / 256, 256, 0, stream>>>(ecol, cnt, NE);
    int M = NN + 1;
    int nscan = (M + 1023) / 1024;
    scan1_kernel<<<nscan, 256, 0, stream>>>(cnt, rp, bsums, dinv, M, NN);
    scan3_kernel<<<(M + 255) / 256, 256, 0, stream>>>(rp, bsums, M);
    place_kernel<<<(NE + 255) / 256, 256, 0, stream>>>(erow, ecol, dinv, rp, fill, csr, NE);

    // weights: slots 1..4 = W^T bf16; slot 0 = fused encoder (W_enc@W0)^T + bias bb
    wconv_kernel<<<(4 * 16384 + 255) / 256, 256, 0, stream>>>(W, Wt);
    fuse_enc_kernel<<<65, 256, 0, stream>>>(W_enc, W, b_enc, Wt, bb);

    int gemmBlocks = (NN + 63) / 64;
    // fused encoder + layer-0 transform: t = x @ (W_enc@W0) + b_enc@W0
    gemm128_mfma<0><<<gemmBlocks, 256, 0, stream>>>(x, Wt, bb, nullptr, t, NN);

    for (int l = 0; l < NL; ++l) {
        if (l > 0)
            gemm128_mfma<2><<<gemmBlocks, 256, 0, stream>>>(
                aggb, Wt + (size_t)(l + 1) * 16384, nullptr, bnp, t, NN);
        aggregate_kernel<<<(NN + 3) / 4, 256, 0, stream>>>(t, rp, csr, dinv,
                                                           b + (size_t)l * HD, aggb, NN);
        bn_stats1_kernel<<<BN_BLOCKS, 512, 0, stream>>>(aggb, partials, NN);
        bn_stats2_kernel<<<1, 256, 0, stream>>>(partials, gamma + (size_t)l * HD,
                                                beta + (size_t)l * HD, bnp, (float)NN);
    }

    pool_cls_kernel<<<NB, 256, 0, stream>>>(aggb, bnp, batch, W_cls, b_cls, out, NN);
}